// Round 9
// baseline (374.983 us; speedup 1.0000x reference)
//
#include <hip/hip_runtime.h>
#include <math.h>

typedef unsigned short u16;
typedef unsigned int   u32;

#define SS_    4
#define NH     4
#define Dh     32
#define Cdim   128
#define Ntok   64
#define WTOT   2048
#define Mrows  131072   // WTOT * Ntok
#define HIDDEN 512
#define PSTR   72       // attn P LDS row stride (u16)
#define OSTR   136      // attn Osm row stride (u16): 272 B, 16-B aligned
#define HPAD   136      // LDS row stride (u16): 272 B, 16-B aligned

typedef __bf16 bf16x8 __attribute__((ext_vector_type(8)));
typedef u16    u16x8  __attribute__((ext_vector_type(8)));
typedef float  f32x4  __attribute__((ext_vector_type(4)));

__device__ __forceinline__ float bf2f(u16 u){
    union {u32 i; float f;} v; v.i = ((u32)u) << 16; return v.f;
}
__device__ __forceinline__ u16 f2bf(float f){
    union {float f; u32 i;} v; v.f = f;
    u32 x = v.i;
    return (u16)((x + 0x7fffu + ((x >> 16) & 1u)) >> 16);
}

// GELU via x*sigmoid(2z) == 0.5x(1+tanh(z)), z = 0.79788456(x+0.044715x^3).
// ~8 VALU ops (vs ~16 for erf-approx); max abs err ~1e-3 (|h| <~ 1.2 here).
__device__ __forceinline__ float fast_gelu(float v){
    float z = v * (1.5957691216057308f + 0.07135481627561976f * v * v);
    return v / (1.0f + __expf(-z));
}

// token (windowed row) -> original token index (bijection, shift +4 both dims)
__device__ __forceinline__ int map_row_to_token(int r){
    int w = r >> 6, n = r & 63;
    int b = w >> 8, win = w & 255;
    int wy = win >> 4, wx = win & 15;
    int iy = n >> 3, ix = n & 7;
    int ro = (wy*8 + iy + SS_) & 127;
    int co = (wx*8 + ix + SS_) & 127;
    return (b << 14) + (ro << 7) + co;
}

// token index -> windowed row (inverse map)
__device__ __forceinline__ int map_token_to_row(int t){
    int b = t >> 14, ro = (t >> 7) & 127, co = t & 127;
    int y  = (ro + 128 - SS_) & 127;
    int xq = (co + 128 - SS_) & 127;
    return (((b << 8) | ((y >> 3) << 4) | (xq >> 3)) << 6) + (y & 7)*8 + (xq & 7);
}

// ---------------- fp32 -> bf16 weight conversion ----------------
__global__ void __launch_bounds__(256) cvt_kernel(const float* __restrict__ src,
        u16* __restrict__ dst, int n)
{
    int i = blockIdx.x * 256 + threadIdx.x;
    if (i < n) dst[i] = f2bf(src[i]);
}

// ---------------- bias+mask table: bm[cls][h][row][col], 4*4*64*64 fp32 ----------
__global__ void __launch_bounds__(256) bm_kernel(const float* __restrict__ rpb,
        float* __restrict__ bmt)
{
    int e = blockIdx.x * 256 + threadIdx.x;     // 65536 total
    int cls = e >> 14, h = (e >> 12) & 3, row = (e >> 6) & 63, col = e & 63;
    int iy = row >> 3, ix = row & 7, jy = col >> 3, jx = col & 7;
    int bidx = (iy - jy + 7)*15 + (ix - jx + 7);
    float bias = rpb[bidx*NH + h];
    int ybit = cls >> 1, xbit = cls & 1;
    int ri = (ybit ? (iy < 4 ? 1 : 2) : 0)*3 + (xbit ? (ix < 4 ? 1 : 2) : 0);
    int rj = (ybit ? (jy < 4 ? 1 : 2) : 0)*3 + (xbit ? (jx < 4 ? 1 : 2) : 0);
    bmt[e] = bias + ((ri != rj) ? -100.0f : 0.0f);
}

// ---- Fused LN1 + QKV GEMM, merged: ONE 512-thread block per 128-row tile
// computes all 384 q/k/v columns. LN1 stage runs ONCE (was 3x across the
// which-split blocks). 8 waves 2x4; each wave covers 96 cols in 2 register
// passes of 48 (acc[4][3] keeps VGPR ~100 -> 4 waves/SIMD).
__global__ void __launch_bounds__(512, 4) ln1qkv_kernel(
        const float* __restrict__ x,
        const float* __restrict__ g, const float* __restrict__ bsh,
        const u16* __restrict__ Bw,      // qkvw_b [384][128]
        const float* __restrict__ bias,  // qkvb [384]
        u16* __restrict__ qb, u16* __restrict__ kb, u16* __restrict__ vb)
{
    __shared__ __align__(16) u16 Asm[128*HPAD];   // 34816 B
    int t = threadIdx.x;
    size_t tilebase = (size_t)blockIdx.x * 128;

    // stage: LN1 over each windowed row (16-lane group owns one row)
    #pragma unroll
    for (int it = 0; it < 4; it++){
        int idx = it*512 + t;
        int rr  = idx >> 4, c8 = idx & 15;
        int trow = (int)tilebase + rr;
        int src  = map_row_to_token(trow);
        f32x4 xa = *(const f32x4*)&x[(size_t)src*Cdim + c8*8];
        f32x4 xb = *(const f32x4*)&x[(size_t)src*Cdim + c8*8 + 4];
        float s = 0.0f, s2 = 0.0f;
        #pragma unroll
        for (int k = 0; k < 4; k++){
            s += xa[k] + xb[k];
            s2 += xa[k]*xa[k] + xb[k]*xb[k];
        }
        #pragma unroll
        for (int off = 1; off <= 8; off <<= 1){
            s  += __shfl_xor(s,  off, 64);
            s2 += __shfl_xor(s2, off, 64);
        }
        float mean = s * (1.0f/128.0f);
        float var  = s2 * (1.0f/128.0f) - mean*mean;
        float inv  = rsqrtf(var + 1e-5f);
        f32x4 ga = *(const f32x4*)&g[c8*8],  gb = *(const f32x4*)&g[c8*8 + 4];
        f32x4 ba = *(const f32x4*)&bsh[c8*8], bb = *(const f32x4*)&bsh[c8*8 + 4];
        u16x8 ov;
        #pragma unroll
        for (int k = 0; k < 4; k++){
            ov[k]   = f2bf((xa[k] - mean) * inv * ga[k] + ba[k]);
            ov[k+4] = f2bf((xb[k] - mean) * inv * gb[k] + bb[k]);
        }
        *(u16x8*)&Asm[rr*HPAD + c8*8] = ov;
    }
    __syncthreads();

    int wave = t >> 6, lane = t & 63;
    int wr = wave & 1, wc = wave >> 1;            // wr: rows, wc: 0..3 col groups
    int m = lane & 15, quad = lane >> 4;

    #pragma unroll
    for (int pass = 0; pass < 2; pass++){
        int colbase = wc*96 + pass*48;
        f32x4 acc[4][3] = {};
        #pragma unroll
        for (int s = 0; s < 4; s++){
            bf16x8 aq[4], bk[3];
            #pragma unroll
            for (int i = 0; i < 4; i++)
                aq[i] = *(const bf16x8*)&Asm[(wr*64 + i*16 + m)*HPAD + s*32 + quad*8];
            #pragma unroll
            for (int j = 0; j < 3; j++)
                bk[j] = *(const bf16x8*)&Bw[(size_t)(colbase + j*16 + m)*Cdim
                                            + s*32 + quad*8];
            #pragma unroll
            for (int i = 0; i < 4; i++)
                #pragma unroll
                for (int j = 0; j < 3; j++)
                    acc[i][j] = __builtin_amdgcn_mfma_f32_16x16x32_bf16(
                                    aq[i], bk[j], acc[i][j], 0, 0, 0);
        }

        // qkv scatter epilogue (q scaled, k normal, v transposed [w][h][d][n])
        #pragma unroll
        for (int j = 0; j < 3; j++){
            int c = colbase + j*16 + m;
            float bia = bias[c];
            int which = c >> 7;
            int h = (c >> 5) & 3;
            int d = c & 31;
            #pragma unroll
            for (int i = 0; i < 4; i++){
                #pragma unroll
                for (int rg = 0; rg < 4; rg++){
                    int r = (int)tilebase + wr*64 + i*16 + quad*4 + rg;
                    float v = acc[i][j][rg] + bia;
                    int w = r >> 6, n = r & 63;
                    if (which == 0){
                        qb[((size_t)(w*NH + h)*Ntok + n)*Dh + d] =
                            f2bf(v * 0.17677669529663687f);
                    } else if (which == 1){
                        kb[((size_t)(w*NH + h)*Ntok + n)*Dh + d] = f2bf(v);
                    } else {
                        vb[((size_t)(w*NH + h)*Dh + d)*Ntok + n] = f2bf(v);
                    }
                }
            }
        }
    }
}

// --- Fused residual + LN2 + MLP, 512-thread blocks (8 waves 2x4):
// 128-row tile, 2 blocks/CU (16 waves/CU), weights L2-resident.
__global__ void __launch_bounds__(512, 4) mlp_kernel(
        const float* __restrict__ x,     // [Mrows][128] fp32, token order
        const u16* __restrict__ projout, // [Mrows][128] bf16, windowed order
        const float* __restrict__ g, const float* __restrict__ bsh,
        const u16* __restrict__ W1,      // fc1w [512][128] bf16
        const float* __restrict__ b1,
        const u16* __restrict__ W2,      // fc2w [128][512] bf16
        const float* __restrict__ b2,
        float* __restrict__ outp)        // out  [Mrows][128] fp32
{
    __shared__ __align__(16) u16 Asm[128*HPAD];
    __shared__ __align__(16) u16 Hsm[128*HPAD];
    int t = threadIdx.x;
    int wave = t >> 6, lane = t & 63;
    int wr = wave & 1, wc = wave >> 1;           // wr: 0..1 (rows), wc: 0..3 (cols)
    int m = lane & 15, quad = lane >> 4;
    size_t rowbase = (size_t)blockIdx.x * 128;

    // ---- fused stage: val = x + proj~, LN2 -> bf16 Asm tile ----
    #pragma unroll
    for (int it = 0; it < 4; it++){
        int idx  = it*512 + t;
        int r    = idx >> 4, c8 = idx & 15;
        int trow = (int)rowbase + r;
        int rr   = map_token_to_row(trow);
        f32x4 xa = *(const f32x4*)&x[(size_t)trow*Cdim + c8*8];
        f32x4 xb = *(const f32x4*)&x[(size_t)trow*Cdim + c8*8 + 4];
        u16x8 pv = *(const u16x8*)&projout[(size_t)rr*Cdim + c8*8];
        float val[8];
        float s = 0.0f, s2 = 0.0f;
        #pragma unroll
        for (int k = 0; k < 8; k++){
            float xv = (k < 4) ? xa[k] : xb[k-4];
            val[k] = xv + bf2f(pv[k]);
            s += val[k]; s2 += val[k]*val[k];
        }
        #pragma unroll
        for (int off = 1; off <= 8; off <<= 1){
            s  += __shfl_xor(s,  off, 64);
            s2 += __shfl_xor(s2, off, 64);
        }
        float mean = s * (1.0f/128.0f);
        float var  = s2 * (1.0f/128.0f) - mean*mean;
        float inv  = rsqrtf(var + 1e-5f);
        f32x4 ga = *(const f32x4*)&g[c8*8],  gb = *(const f32x4*)&g[c8*8 + 4];
        f32x4 ba = *(const f32x4*)&bsh[c8*8], bb = *(const f32x4*)&bsh[c8*8 + 4];
        u16x8 ov;
        #pragma unroll
        for (int k = 0; k < 8; k++){
            float gv = (k < 4) ? ga[k] : gb[k-4];
            float bv = (k < 4) ? ba[k] : bb[k-4];
            ov[k] = f2bf((val[k] - mean) * inv * gv + bv);
        }
        *(u16x8*)&Asm[r*HPAD + c8*8] = ov;
    }
    __syncthreads();

    f32x4 O[4][2] = {};                  // 64 rows x 32 out cols per wave

    for (int kk = 0; kk < 4; kk++){
        // ---- H chunk: wave (wr,wc) computes rows wr*64..+64, hid cols wc*32..+32
        f32x4 Hacc[4][2] = {};
        #pragma unroll
        for (int s = 0; s < 4; s++){
            bf16x8 aq[4], bk[2];
            #pragma unroll
            for (int i = 0; i < 4; i++)
                aq[i] = *(const bf16x8*)&Asm[(wr*64 + i*16 + m)*HPAD + s*32 + quad*8];
            #pragma unroll
            for (int j = 0; j < 2; j++)
                bk[j] = *(const bf16x8*)&W1[(size_t)(kk*128 + wc*32 + j*16 + m)*Cdim
                                            + s*32 + quad*8];
            #pragma unroll
            for (int i = 0; i < 4; i++)
                #pragma unroll
                for (int j = 0; j < 2; j++)
                    Hacc[i][j] = __builtin_amdgcn_mfma_f32_16x16x32_bf16(
                                     aq[i], bk[j], Hacc[i][j], 0, 0, 0);
        }
        #pragma unroll
        for (int i = 0; i < 4; i++){
            #pragma unroll
            for (int j = 0; j < 2; j++){
                int hc = wc*32 + j*16 + m;          // hidden col within chunk
                float bia = b1[kk*128 + hc];
                #pragma unroll
                for (int rg = 0; rg < 4; rg++){
                    int r = wr*64 + i*16 + quad*4 + rg;
                    Hsm[r*HPAD + hc] = f2bf(fast_gelu(Hacc[i][j][rg] + bia));
                }
            }
        }
        __syncthreads();

        // ---- O += Hc @ W2[:, kk*128 ..]^T  (out cols wc*32..+32) ----
        #pragma unroll
        for (int s = 0; s < 4; s++){
            bf16x8 pa[4], bk[2];
            #pragma unroll
            for (int i = 0; i < 4; i++)
                pa[i] = *(const bf16x8*)&Hsm[(wr*64 + i*16 + m)*HPAD + s*32 + quad*8];
            #pragma unroll
            for (int j = 0; j < 2; j++)
                bk[j] = *(const bf16x8*)&W2[(size_t)(wc*32 + j*16 + m)*HIDDEN
                                            + kk*128 + s*32 + quad*8];
            #pragma unroll
            for (int i = 0; i < 4; i++)
                #pragma unroll
                for (int j = 0; j < 2; j++)
                    O[i][j] = __builtin_amdgcn_mfma_f32_16x16x32_bf16(
                                  pa[i], bk[j], O[i][j], 0, 0, 0);
        }
        __syncthreads();   // Hsm reused next chunk
    }

    // ---- epilogue: out = (x + proj~) + O + b2 (x/proj re-read; L2-hot) ----
    #pragma unroll
    for (int i = 0; i < 4; i++){
        #pragma unroll
        for (int rg = 0; rg < 4; rg++){
            int r  = (int)rowbase + wr*64 + i*16 + quad*4 + rg;   // token row
            int rr = map_token_to_row(r);
            #pragma unroll
            for (int j = 0; j < 2; j++){
                int c = wc*32 + j*16 + m;
                float v = x[(size_t)r*Cdim + c] + bf2f(projout[(size_t)rr*Cdim + c])
                          + O[i][j][rg] + b2[c];
                outp[(size_t)r*Cdim + c] = v;
            }
        }
    }
}

// ------- Fused attention + proj: block = window, wave = head -------------------
__global__ void __launch_bounds__(256) attnproj_kernel(
        const u16* __restrict__ qb, const u16* __restrict__ kb,
        const u16* __restrict__ vt, const float* __restrict__ bmt,
        const u16* __restrict__ pw, const float* __restrict__ pb,
        u16* __restrict__ projout)
{
    __shared__ __align__(16) u16 SH[NH*64*PSTR];   // 36864 B; P + (union) Osm
    int w = blockIdx.x;
    int win = w & 255;
    int wy = win >> 4, wx = win & 15;
    int cls = ((wy == 15) ? 2 : 0) | ((wx == 15) ? 1 : 0);
    int t = threadIdx.x;
    int h = t >> 6, lane = t & 63;
    int m = lane & 15, quad = lane >> 4;
    u16* Ph  = SH + h*64*PSTR;     // per-wave private P rows
    u16* Osm = SH;                 // 64 x OSTR union view (after barrier 1)

    const u16* qg = qb + (size_t)(w*NH + h)*2048;   // [n][d]
    const u16* kg = kb + (size_t)(w*NH + h)*2048;   // [n][d]
    const u16* vg = vt + (size_t)(w*NH + h)*2048;   // [d][n] (transposed)
    const float* bm = bmt + (size_t)(cls*NH + h)*4096;

    // S = Q @ K^T  (64x64, one K=32 step)
    bf16x8 aq[4], bk[4];
    #pragma unroll
    for (int i = 0; i < 4; i++)
        aq[i] = *(const bf16x8*)&qg[(i*16 + m)*32 + quad*8];
    #pragma unroll
    for (int j = 0; j < 4; j++)
        bk[j] = *(const bf16x8*)&kg[(j*16 + m)*32 + quad*8];
    f32x4 S[4][4] = {};
    #pragma unroll
    for (int i = 0; i < 4; i++)
        #pragma unroll
        for (int j = 0; j < 4; j++)
            S[i][j] = __builtin_amdgcn_mfma_f32_16x16x32_bf16(
                          aq[i], bk[j], S[i][j], 0, 0, 0);

    // bias+mask add, row softmax -> P (bf16, per-wave private; no barrier)
    #pragma unroll
    for (int i = 0; i < 4; i++){
        #pragma unroll
        for (int rg = 0; rg < 4; rg++){
            int row = i*16 + quad*4 + rg;
            float s0 = S[i][0][rg] + bm[row*64 +  0 + m];
            float s1 = S[i][1][rg] + bm[row*64 + 16 + m];
            float s2 = S[i][2][rg] + bm[row*64 + 32 + m];
            float s3 = S[i][3][rg] + bm[row*64 + 48 + m];
            float mx = fmaxf(fmaxf(s0, s1), fmaxf(s2, s3));
            mx = fmaxf(mx, __shfl_xor(mx, 1, 64));
            mx = fmaxf(mx, __shfl_xor(mx, 2, 64));
            mx = fmaxf(mx, __shfl_xor(mx, 4, 64));
            mx = fmaxf(mx, __shfl_xor(mx, 8, 64));
            s0 = __expf(s0 - mx); s1 = __expf(s1 - mx);
            s2 = __expf(s2 - mx); s3 = __expf(s3 - mx);
            float sm = s0 + s1 + s2 + s3;
            sm += __shfl_xor(sm, 1, 64);
            sm += __shfl_xor(sm, 2, 64);
            sm += __shfl_xor(sm, 4, 64);
            sm += __shfl_xor(sm, 8, 64);
            float rinv = 1.0f / sm;
            u16* pr = &Ph[row*PSTR];
            pr[ 0 + m] = f2bf(s0 * rinv);
            pr[16 + m] = f2bf(s1 * rinv);
            pr[32 + m] = f2bf(s2 * rinv);
            pr[48 + m] = f2bf(s3 * rinv);
        }
    }

    // O = P @ V  (64x32, two K=32 steps)
    f32x4 O[4][2] = {};
    #pragma unroll
    for (int s2 = 0; s2 < 2; s2++){
        bf16x8 pa[4], bv[2];
        #pragma unroll
        for (int i = 0; i < 4; i++)
            pa[i] = *(const bf16x8*)&Ph[(i*16 + m)*PSTR + s2*32 + quad*8];
        #pragma unroll
        for (int dt = 0; dt < 2; dt++)
            bv[dt] = *(const bf16x8*)&vg[(dt*16 + m)*64 + s2*32 + quad*8];
        #pragma unroll
        for (int i = 0; i < 4; i++)
            #pragma unroll
            for (int dt = 0; dt < 2; dt++)
                O[i][dt] = __builtin_amdgcn_mfma_f32_16x16x32_bf16(
                               pa[i], bv[dt], O[i][dt], 0, 0, 0);
    }

    __syncthreads();   // all P reads done; SH is reused as Osm below

    // stage head-concat tile: Osm[row][h*32 + dt*16 + m]
    #pragma unroll
    for (int i = 0; i < 4; i++)
        #pragma unroll
        for (int dt = 0; dt < 2; dt++)
            #pragma unroll
            for (int rg = 0; rg < 4; rg++)
                Osm[(i*16 + quad*4 + rg)*OSTR + h*Dh + dt*16 + m] =
                    f2bf(O[i][dt][rg]);
    __syncthreads();

    // proj GEMM: 64x128x128; wave h covers out cols [h*32, h*32+32)
    f32x4 pacc[4][2] = {};
    #pragma unroll
    for (int s = 0; s < 4; s++){
        bf16x8 pa[4], pbk[2];
        #pragma unroll
        for (int i = 0; i < 4; i++)
            pa[i] = *(const bf16x8*)&Osm[(i*16 + m)*OSTR + s*32 + quad*8];
        #pragma unroll
        for (int j = 0; j < 2; j++)
            pbk[j] = *(const bf16x8*)&pw[(size_t)(h*Dh + j*16 + m)*Cdim
                                         + s*32 + quad*8];
        #pragma unroll
        for (int i = 0; i < 4; i++)
            #pragma unroll
            for (int j = 0; j < 2; j++)
                pacc[i][j] = __builtin_amdgcn_mfma_f32_16x16x32_bf16(
                                 pa[i], pbk[j], pacc[i][j], 0, 0, 0);
    }
    __syncthreads();   // all Osm reads done

    // stage proj result (+bias) back into Osm
    #pragma unroll
    for (int i = 0; i < 4; i++)
        #pragma unroll
        for (int j = 0; j < 2; j++){
            int c = h*Dh + j*16 + m;
            float bia = pb[c];
            #pragma unroll
            for (int rg = 0; rg < 4; rg++)
                Osm[(i*16 + quad*4 + rg)*OSTR + c] = f2bf(pacc[i][j][rg] + bia);
        }
    __syncthreads();

    // coalesced store: 64 rows x 128 u16 = 1024 chunks of 16 B
    #pragma unroll
    for (int it = 0; it < 4; it++){
        int idx = it*256 + t;
        int r = idx >> 4, c16 = idx & 15;
        *(bf16x8*)&projout[((size_t)w*64 + r)*Cdim + c16*8] =
            *(const bf16x8*)&Osm[r*OSTR + c16*8];
    }
}

extern "C" void kernel_launch(void* const* d_in, const int* in_sizes, int n_in,
                              void* d_out, int out_size, void* d_ws, size_t ws_size,
                              hipStream_t stream) {
    const float* x     = (const float*)d_in[0];
    const float* rpb   = (const float*)d_in[1];
    const float* n1g   = (const float*)d_in[2];
    const float* n1b   = (const float*)d_in[3];
    const float* qkvw  = (const float*)d_in[4];
    const float* qkvb  = (const float*)d_in[5];
    const float* projw = (const float*)d_in[6];
    const float* projb = (const float*)d_in[7];
    const float* n2g   = (const float*)d_in[8];
    const float* n2b   = (const float*)d_in[9];
    const float* fc1w  = (const float*)d_in[10];
    const float* fc1b  = (const float*)d_in[11];
    const float* fc2w  = (const float*)d_in[12];
    const float* fc2b  = (const float*)d_in[13];
    float* out = (float*)d_out;

    if (ws_size < (size_t)230u * 1024u * 1024u) return;

    // Disjoint-lifetime layout (race-free):
    //   region        offset   size   lifetime
    //   projout       0        32M    s2 -> s3
    //   qbuf          32M      32M    s1 -> s2
    //   kbuf          64M      32M    s1 -> s2
    //   vbuf          96M      32M    s1 -> s2
    //   weights/bmt   224M     ~2M    s0 -> end
    char* ws = (char*)d_ws;
    u16*  projout = (u16*)(ws);
    u16*  qbuf    = (u16*)(ws + ((size_t)32  << 20));
    u16*  kbuf    = (u16*)(ws + ((size_t)64  << 20));
    u16*  vbuf    = (u16*)(ws + ((size_t)96  << 20));
    u16*  wb      = (u16*)(ws + ((size_t)224 << 20));
    u16*  qkvw_b  = wb;                // 49152
    u16*  projw_b = wb + 49152;        // 16384
    u16*  fc1w_b  = wb + 65536;        // 65536
    u16*  fc2w_b  = wb + 131072;       // 65536
    float* bmt    = (float*)(ws + ((size_t)225 << 20)); // 256 KiB

    // 0. weight conversions + bias/mask table
    cvt_kernel<<<(49152+255)/256, 256, 0, stream>>>(qkvw, qkvw_b, 49152);
    cvt_kernel<<<(16384+255)/256, 256, 0, stream>>>(projw, projw_b, 16384);
    cvt_kernel<<<(65536+255)/256, 256, 0, stream>>>(fc1w, fc1w_b, 65536);
    cvt_kernel<<<(65536+255)/256, 256, 0, stream>>>(fc2w, fc2w_b, 65536);
    bm_kernel<<<256, 256, 0, stream>>>(rpb, bmt);

    // 1. fused LN1 + QKV GEMM (merged: one 512-thr block per tile, stage once)
    ln1qkv_kernel<<<Mrows/128, 512, 0, stream>>>(
        x, n1g, n1b, qkvw_b, qkvb, qbuf, kbuf, vbuf);
    // 2. fused MFMA windowed attention + proj (block = window)
    attnproj_kernel<<<WTOT, 256, 0, stream>>>(qbuf, kbuf, vbuf, bmt,
                                              projw_b, projb, projout);
    // 3. fused residual + LN2 + MLP -> out (128-row tiles, 512-thr blocks,
    //    16 waves/CU)
    mlp_kernel<<<Mrows/128, 512, 0, stream>>>(
        x, projout, n2g, n2b, fc1w_b, fc1b, fc2w_b, fc2b, out);
}

// Round 10
// 328.667 us; speedup vs baseline: 1.1409x; 1.1409x over previous
//
#include <hip/hip_runtime.h>
#include <math.h>

typedef unsigned short u16;
typedef unsigned int   u32;

#define SS_    4
#define NH     4
#define Dh     32
#define Cdim   128
#define Ntok   64
#define WTOT   2048
#define Mrows  131072   // WTOT * Ntok
#define HIDDEN 512
#define PSTR   72       // attn P LDS row stride (u16)
#define OSTR   136      // attn Osm row stride (u16): 272 B, 16-B aligned
#define HPAD   136      // LDS row stride (u16): 272 B, 16-B aligned
#define VSTR   68       // Vsm n-stride (u16): 136 B -> bank-spread, 8-B aligned

typedef __bf16 bf16x8 __attribute__((ext_vector_type(8)));
typedef u16    u16x8  __attribute__((ext_vector_type(8)));
typedef u16    u16x4  __attribute__((ext_vector_type(4)));
typedef float  f32x4  __attribute__((ext_vector_type(4)));

__device__ __forceinline__ float bf2f(u16 u){
    union {u32 i; float f;} v; v.i = ((u32)u) << 16; return v.f;
}
__device__ __forceinline__ u16 f2bf(float f){
    union {float f; u32 i;} v; v.f = f;
    u32 x = v.i;
    return (u16)((x + 0x7fffu + ((x >> 16) & 1u)) >> 16);
}

// GELU via x*sigmoid(2z) == 0.5x(1+tanh(z)), z = 0.79788456(x+0.044715x^3).
__device__ __forceinline__ float fast_gelu(float v){
    float z = v * (1.5957691216057308f + 0.07135481627561976f * v * v);
    return v / (1.0f + __expf(-z));
}

// token (windowed row) -> original token index (bijection, shift +4 both dims)
__device__ __forceinline__ int map_row_to_token(int r){
    int w = r >> 6, n = r & 63;
    int b = w >> 8, win = w & 255;
    int wy = win >> 4, wx = win & 15;
    int iy = n >> 3, ix = n & 7;
    int ro = (wy*8 + iy + SS_) & 127;
    int co = (wx*8 + ix + SS_) & 127;
    return (b << 14) + (ro << 7) + co;
}

// token index -> windowed row (inverse map)
__device__ __forceinline__ int map_token_to_row(int t){
    int b = t >> 14, ro = (t >> 7) & 127, co = t & 127;
    int y  = (ro + 128 - SS_) & 127;
    int xq = (co + 128 - SS_) & 127;
    return (((b << 8) | ((y >> 3) << 4) | (xq >> 3)) << 6) + (y & 7)*8 + (xq & 7);
}

// ---------------- fp32 -> bf16 weight conversion ----------------
__global__ void __launch_bounds__(256) cvt_kernel(const float* __restrict__ src,
        u16* __restrict__ dst, int n)
{
    int i = blockIdx.x * 256 + threadIdx.x;
    if (i < n) dst[i] = f2bf(src[i]);
}

// ---------------- bias+mask table: bm[cls][h][row][col], 4*4*64*64 fp32 ----------
__global__ void __launch_bounds__(256) bm_kernel(const float* __restrict__ rpb,
        float* __restrict__ bmt)
{
    int e = blockIdx.x * 256 + threadIdx.x;     // 65536 total
    int cls = e >> 14, h = (e >> 12) & 3, row = (e >> 6) & 63, col = e & 63;
    int iy = row >> 3, ix = row & 7, jy = col >> 3, jx = col & 7;
    int bidx = (iy - jy + 7)*15 + (ix - jx + 7);
    float bias = rpb[bidx*NH + h];
    int ybit = cls >> 1, xbit = cls & 1;
    int ri = (ybit ? (iy < 4 ? 1 : 2) : 0)*3 + (xbit ? (ix < 4 ? 1 : 2) : 0);
    int rj = (ybit ? (jy < 4 ? 1 : 2) : 0)*3 + (xbit ? (jx < 4 ? 1 : 2) : 0);
    bmt[e] = bias + ((ri != rj) ? -100.0f : 0.0f);
}

// ---- Fused LN1 + QKV GEMM, one 512-thread block per 128-row tile.
// Pass 0 = cols 0..191 (q + k-low, direct stores); pass 1 = cols 192..383
// (k-high direct, v staged through Asm-reused-as-Vsm for COALESCED transposed
// stores -- fixes the 2.5x write amplification of the per-element v scatter).
__global__ void __launch_bounds__(512, 4) ln1qkv_kernel(
        const float* __restrict__ x,
        const float* __restrict__ g, const float* __restrict__ bsh,
        const u16* __restrict__ Bw,      // qkvw_b [384][128]
        const float* __restrict__ bias,  // qkvb [384]
        u16* __restrict__ qb, u16* __restrict__ kb, u16* __restrict__ vb)
{
    __shared__ __align__(16) u16 Asm[128*HPAD];   // 34816 B; reused as Vsm
    int t = threadIdx.x;
    size_t tilebase = (size_t)blockIdx.x * 128;

    // stage: LN1 over each windowed row (16-lane group owns one row)
    #pragma unroll
    for (int it = 0; it < 4; it++){
        int idx = it*512 + t;
        int rr  = idx >> 4, c8 = idx & 15;
        int trow = (int)tilebase + rr;
        int src  = map_row_to_token(trow);
        f32x4 xa = *(const f32x4*)&x[(size_t)src*Cdim + c8*8];
        f32x4 xb = *(const f32x4*)&x[(size_t)src*Cdim + c8*8 + 4];
        float s = 0.0f, s2 = 0.0f;
        #pragma unroll
        for (int k = 0; k < 4; k++){
            s += xa[k] + xb[k];
            s2 += xa[k]*xa[k] + xb[k]*xb[k];
        }
        #pragma unroll
        for (int off = 1; off <= 8; off <<= 1){
            s  += __shfl_xor(s,  off, 64);
            s2 += __shfl_xor(s2, off, 64);
        }
        float mean = s * (1.0f/128.0f);
        float var  = s2 * (1.0f/128.0f) - mean*mean;
        float inv  = rsqrtf(var + 1e-5f);
        f32x4 ga = *(const f32x4*)&g[c8*8],  gb = *(const f32x4*)&g[c8*8 + 4];
        f32x4 ba = *(const f32x4*)&bsh[c8*8], bb = *(const f32x4*)&bsh[c8*8 + 4];
        u16x8 ov;
        #pragma unroll
        for (int k = 0; k < 4; k++){
            ov[k]   = f2bf((xa[k] - mean) * inv * ga[k] + ba[k]);
            ov[k+4] = f2bf((xb[k] - mean) * inv * gb[k] + bb[k]);
        }
        *(u16x8*)&Asm[rr*HPAD + c8*8] = ov;
    }
    __syncthreads();

    int wave = t >> 6, lane = t & 63;
    int wr = wave & 1, wc = wave >> 1;            // wr: rows, wc: 0..3 col groups
    int m = lane & 15, quad = lane >> 4;

    // ---- pass 0: cols 0..191 (q and low k), direct global stores ----
    {
        int colbase = wc*48;
        f32x4 acc[4][3] = {};
        #pragma unroll
        for (int s = 0; s < 4; s++){
            bf16x8 aq[4], bk[3];
            #pragma unroll
            for (int i = 0; i < 4; i++)
                aq[i] = *(const bf16x8*)&Asm[(wr*64 + i*16 + m)*HPAD + s*32 + quad*8];
            #pragma unroll
            for (int j = 0; j < 3; j++)
                bk[j] = *(const bf16x8*)&Bw[(size_t)(colbase + j*16 + m)*Cdim
                                            + s*32 + quad*8];
            #pragma unroll
            for (int i = 0; i < 4; i++)
                #pragma unroll
                for (int j = 0; j < 3; j++)
                    acc[i][j] = __builtin_amdgcn_mfma_f32_16x16x32_bf16(
                                    aq[i], bk[j], acc[i][j], 0, 0, 0);
        }
        #pragma unroll
        for (int j = 0; j < 3; j++){
            int c = colbase + j*16 + m;
            float bia = bias[c];
            int which = c >> 7;                   // 0=q 1=k (no v in pass 0)
            int h = (c >> 5) & 3;
            int d = c & 31;
            #pragma unroll
            for (int i = 0; i < 4; i++){
                #pragma unroll
                for (int rg = 0; rg < 4; rg++){
                    int r = (int)tilebase + wr*64 + i*16 + quad*4 + rg;
                    float v = acc[i][j][rg] + bia;
                    int w = r >> 6, n = r & 63;
                    if (which == 0){
                        qb[((size_t)(w*NH + h)*Ntok + n)*Dh + d] =
                            f2bf(v * 0.17677669529663687f);
                    } else {
                        kb[((size_t)(w*NH + h)*Ntok + n)*Dh + d] = f2bf(v);
                    }
                }
            }
        }
    }

    // ---- pass 1: cols 192..383 (high k direct; v -> Vsm -> coalesced) ----
    {
        int colbase = 192 + wc*48;
        f32x4 acc[4][3] = {};
        #pragma unroll
        for (int s = 0; s < 4; s++){
            bf16x8 aq[4], bk[3];
            #pragma unroll
            for (int i = 0; i < 4; i++)
                aq[i] = *(const bf16x8*)&Asm[(wr*64 + i*16 + m)*HPAD + s*32 + quad*8];
            #pragma unroll
            for (int j = 0; j < 3; j++)
                bk[j] = *(const bf16x8*)&Bw[(size_t)(colbase + j*16 + m)*Cdim
                                            + s*32 + quad*8];
            #pragma unroll
            for (int i = 0; i < 4; i++)
                #pragma unroll
                for (int j = 0; j < 3; j++)
                    acc[i][j] = __builtin_amdgcn_mfma_f32_16x16x32_bf16(
                                    aq[i], bk[j], acc[i][j], 0, 0, 0);
        }
        // direct k stores (c < 256)
        #pragma unroll
        for (int j = 0; j < 3; j++){
            int c = colbase + j*16 + m;
            if ((c >> 7) == 1){
                float bia = bias[c];
                int h = (c >> 5) & 3;
                int d = c & 31;
                #pragma unroll
                for (int i = 0; i < 4; i++){
                    #pragma unroll
                    for (int rg = 0; rg < 4; rg++){
                        int r = (int)tilebase + wr*64 + i*16 + quad*4 + rg;
                        int w = r >> 6, n = r & 63;
                        kb[((size_t)(w*NH + h)*Ntok + n)*Dh + d] =
                            f2bf(acc[i][j][rg] + bia);
                    }
                }
            }
        }
        __syncthreads();   // all Asm MFMA reads complete; reuse as Vsm

        // v groups -> Vsm[w2][h][d][n] with n-stride VSTR (bank-spread)
        u16* Vsm = Asm;
        #pragma unroll
        for (int j = 0; j < 3; j++){
            int c = colbase + j*16 + m;
            if ((c >> 7) == 2){
                float bia = bias[c];
                int h = (c >> 5) & 3;
                int d = c & 31;
                #pragma unroll
                for (int i = 0; i < 4; i++){
                    #pragma unroll
                    for (int rg = 0; rg < 4; rg++){
                        int lr = wr*64 + i*16 + quad*4 + rg;   // local row
                        int w2 = lr >> 6, n = lr & 63;
                        Vsm[((w2*NH + h)*Dh + d)*VSTR + n] =
                            f2bf(acc[i][j][rg] + bia);
                    }
                }
            }
        }
        __syncthreads();

        // coalesced v store: 256 d-rows x 64 n = 4096 chunks of 8 B
        size_t vbase = (size_t)blockIdx.x * 16384;   // 2 windows * 4h * 32d * 64n
        #pragma unroll
        for (int it = 0; it < 8; it++){
            int ck = it*512 + t;
            int dr = ck >> 4, nc = ck & 15;
            *(u16x4*)&vb[vbase + (size_t)dr*64 + nc*4] =
                *(const u16x4*)&Vsm[dr*VSTR + nc*4];
        }
    }
}

// --- Fused residual + LN2 + MLP, 512-thread blocks (8 waves 2x4):
// 128-row tile, 2 blocks/CU (16 waves/CU), weights L2-resident.
__global__ void __launch_bounds__(512, 4) mlp_kernel(
        const float* __restrict__ x,     // [Mrows][128] fp32, token order
        const u16* __restrict__ projout, // [Mrows][128] bf16, windowed order
        const float* __restrict__ g, const float* __restrict__ bsh,
        const u16* __restrict__ W1,      // fc1w [512][128] bf16
        const float* __restrict__ b1,
        const u16* __restrict__ W2,      // fc2w [128][512] bf16
        const float* __restrict__ b2,
        float* __restrict__ outp)        // out  [Mrows][128] fp32
{
    __shared__ __align__(16) u16 Asm[128*HPAD];
    __shared__ __align__(16) u16 Hsm[128*HPAD];
    int t = threadIdx.x;
    int wave = t >> 6, lane = t & 63;
    int wr = wave & 1, wc = wave >> 1;           // wr: 0..1 (rows), wc: 0..3 (cols)
    int m = lane & 15, quad = lane >> 4;
    size_t rowbase = (size_t)blockIdx.x * 128;

    // ---- fused stage: val = x + proj~, LN2 -> bf16 Asm tile ----
    #pragma unroll
    for (int it = 0; it < 4; it++){
        int idx  = it*512 + t;
        int r    = idx >> 4, c8 = idx & 15;
        int trow = (int)rowbase + r;
        int rr   = map_token_to_row(trow);
        f32x4 xa = *(const f32x4*)&x[(size_t)trow*Cdim + c8*8];
        f32x4 xb = *(const f32x4*)&x[(size_t)trow*Cdim + c8*8 + 4];
        u16x8 pv = *(const u16x8*)&projout[(size_t)rr*Cdim + c8*8];
        float val[8];
        float s = 0.0f, s2 = 0.0f;
        #pragma unroll
        for (int k = 0; k < 8; k++){
            float xv = (k < 4) ? xa[k] : xb[k-4];
            val[k] = xv + bf2f(pv[k]);
            s += val[k]; s2 += val[k]*val[k];
        }
        #pragma unroll
        for (int off = 1; off <= 8; off <<= 1){
            s  += __shfl_xor(s,  off, 64);
            s2 += __shfl_xor(s2, off, 64);
        }
        float mean = s * (1.0f/128.0f);
        float var  = s2 * (1.0f/128.0f) - mean*mean;
        float inv  = rsqrtf(var + 1e-5f);
        f32x4 ga = *(const f32x4*)&g[c8*8],  gb = *(const f32x4*)&g[c8*8 + 4];
        f32x4 ba = *(const f32x4*)&bsh[c8*8], bb = *(const f32x4*)&bsh[c8*8 + 4];
        u16x8 ov;
        #pragma unroll
        for (int k = 0; k < 8; k++){
            float gv = (k < 4) ? ga[k] : gb[k-4];
            float bv = (k < 4) ? ba[k] : bb[k-4];
            ov[k] = f2bf((val[k] - mean) * inv * gv + bv);
        }
        *(u16x8*)&Asm[r*HPAD + c8*8] = ov;
    }
    __syncthreads();

    f32x4 O[4][2] = {};                  // 64 rows x 32 out cols per wave

    for (int kk = 0; kk < 4; kk++){
        // ---- H chunk: wave (wr,wc) computes rows wr*64..+64, hid cols wc*32..+32
        f32x4 Hacc[4][2] = {};
        #pragma unroll
        for (int s = 0; s < 4; s++){
            bf16x8 aq[4], bk[2];
            #pragma unroll
            for (int i = 0; i < 4; i++)
                aq[i] = *(const bf16x8*)&Asm[(wr*64 + i*16 + m)*HPAD + s*32 + quad*8];
            #pragma unroll
            for (int j = 0; j < 2; j++)
                bk[j] = *(const bf16x8*)&W1[(size_t)(kk*128 + wc*32 + j*16 + m)*Cdim
                                            + s*32 + quad*8];
            #pragma unroll
            for (int i = 0; i < 4; i++)
                #pragma unroll
                for (int j = 0; j < 2; j++)
                    Hacc[i][j] = __builtin_amdgcn_mfma_f32_16x16x32_bf16(
                                     aq[i], bk[j], Hacc[i][j], 0, 0, 0);
        }
        #pragma unroll
        for (int i = 0; i < 4; i++){
            #pragma unroll
            for (int j = 0; j < 2; j++){
                int hc = wc*32 + j*16 + m;          // hidden col within chunk
                float bia = b1[kk*128 + hc];
                #pragma unroll
                for (int rg = 0; rg < 4; rg++){
                    int r = wr*64 + i*16 + quad*4 + rg;
                    Hsm[r*HPAD + hc] = f2bf(fast_gelu(Hacc[i][j][rg] + bia));
                }
            }
        }
        __syncthreads();

        // ---- O += Hc @ W2[:, kk*128 ..]^T  (out cols wc*32..+32) ----
        #pragma unroll
        for (int s = 0; s < 4; s++){
            bf16x8 pa[4], bk[2];
            #pragma unroll
            for (int i = 0; i < 4; i++)
                pa[i] = *(const bf16x8*)&Hsm[(wr*64 + i*16 + m)*HPAD + s*32 + quad*8];
            #pragma unroll
            for (int j = 0; j < 2; j++)
                bk[j] = *(const bf16x8*)&W2[(size_t)(wc*32 + j*16 + m)*HIDDEN
                                            + kk*128 + s*32 + quad*8];
            #pragma unroll
            for (int i = 0; i < 4; i++)
                #pragma unroll
                for (int j = 0; j < 2; j++)
                    O[i][j] = __builtin_amdgcn_mfma_f32_16x16x32_bf16(
                                  pa[i], bk[j], O[i][j], 0, 0, 0);
        }
        __syncthreads();   // Hsm reused next chunk
    }

    // ---- epilogue: out = (x + proj~) + O + b2 (x/proj re-read; L2-hot) ----
    #pragma unroll
    for (int i = 0; i < 4; i++){
        #pragma unroll
        for (int rg = 0; rg < 4; rg++){
            int r  = (int)rowbase + wr*64 + i*16 + quad*4 + rg;   // token row
            int rr = map_token_to_row(r);
            #pragma unroll
            for (int j = 0; j < 2; j++){
                int c = wc*32 + j*16 + m;
                float v = x[(size_t)r*Cdim + c] + bf2f(projout[(size_t)rr*Cdim + c])
                          + O[i][j][rg] + b2[c];
                outp[(size_t)r*Cdim + c] = v;
            }
        }
    }
}

// ------- Fused attention + proj: block = window, wave = head -------------------
__global__ void __launch_bounds__(256) attnproj_kernel(
        const u16* __restrict__ qb, const u16* __restrict__ kb,
        const u16* __restrict__ vt, const float* __restrict__ bmt,
        const u16* __restrict__ pw, const float* __restrict__ pb,
        u16* __restrict__ projout)
{
    __shared__ __align__(16) u16 SH[NH*64*PSTR];   // 36864 B; P + (union) Osm
    int w = blockIdx.x;
    int win = w & 255;
    int wy = win >> 4, wx = win & 15;
    int cls = ((wy == 15) ? 2 : 0) | ((wx == 15) ? 1 : 0);
    int t = threadIdx.x;
    int h = t >> 6, lane = t & 63;
    int m = lane & 15, quad = lane >> 4;
    u16* Ph  = SH + h*64*PSTR;     // per-wave private P rows
    u16* Osm = SH;                 // 64 x OSTR union view (after barrier 1)

    const u16* qg = qb + (size_t)(w*NH + h)*2048;   // [n][d]
    const u16* kg = kb + (size_t)(w*NH + h)*2048;   // [n][d]
    const u16* vg = vt + (size_t)(w*NH + h)*2048;   // [d][n] (transposed)
    const float* bm = bmt + (size_t)(cls*NH + h)*4096;

    // S = Q @ K^T  (64x64, one K=32 step)
    bf16x8 aq[4], bk[4];
    #pragma unroll
    for (int i = 0; i < 4; i++)
        aq[i] = *(const bf16x8*)&qg[(i*16 + m)*32 + quad*8];
    #pragma unroll
    for (int j = 0; j < 4; j++)
        bk[j] = *(const bf16x8*)&kg[(j*16 + m)*32 + quad*8];
    f32x4 S[4][4] = {};
    #pragma unroll
    for (int i = 0; i < 4; i++)
        #pragma unroll
        for (int j = 0; j < 4; j++)
            S[i][j] = __builtin_amdgcn_mfma_f32_16x16x32_bf16(
                          aq[i], bk[j], S[i][j], 0, 0, 0);

    // bias+mask add, row softmax -> P (bf16, per-wave private; no barrier)
    #pragma unroll
    for (int i = 0; i < 4; i++){
        #pragma unroll
        for (int rg = 0; rg < 4; rg++){
            int row = i*16 + quad*4 + rg;
            float s0 = S[i][0][rg] + bm[row*64 +  0 + m];
            float s1 = S[i][1][rg] + bm[row*64 + 16 + m];
            float s2 = S[i][2][rg] + bm[row*64 + 32 + m];
            float s3 = S[i][3][rg] + bm[row*64 + 48 + m];
            float mx = fmaxf(fmaxf(s0, s1), fmaxf(s2, s3));
            mx = fmaxf(mx, __shfl_xor(mx, 1, 64));
            mx = fmaxf(mx, __shfl_xor(mx, 2, 64));
            mx = fmaxf(mx, __shfl_xor(mx, 4, 64));
            mx = fmaxf(mx, __shfl_xor(mx, 8, 64));
            s0 = __expf(s0 - mx); s1 = __expf(s1 - mx);
            s2 = __expf(s2 - mx); s3 = __expf(s3 - mx);
            float sm = s0 + s1 + s2 + s3;
            sm += __shfl_xor(sm, 1, 64);
            sm += __shfl_xor(sm, 2, 64);
            sm += __shfl_xor(sm, 4, 64);
            sm += __shfl_xor(sm, 8, 64);
            float rinv = 1.0f / sm;
            u16* pr = &Ph[row*PSTR];
            pr[ 0 + m] = f2bf(s0 * rinv);
            pr[16 + m] = f2bf(s1 * rinv);
            pr[32 + m] = f2bf(s2 * rinv);
            pr[48 + m] = f2bf(s3 * rinv);
        }
    }

    // O = P @ V  (64x32, two K=32 steps)
    f32x4 O[4][2] = {};
    #pragma unroll
    for (int s2 = 0; s2 < 2; s2++){
        bf16x8 pa[4], bv[2];
        #pragma unroll
        for (int i = 0; i < 4; i++)
            pa[i] = *(const bf16x8*)&Ph[(i*16 + m)*PSTR + s2*32 + quad*8];
        #pragma unroll
        for (int dt = 0; dt < 2; dt++)
            bv[dt] = *(const bf16x8*)&vg[(dt*16 + m)*64 + s2*32 + quad*8];
        #pragma unroll
        for (int i = 0; i < 4; i++)
            #pragma unroll
            for (int dt = 0; dt < 2; dt++)
                O[i][dt] = __builtin_amdgcn_mfma_f32_16x16x32_bf16(
                               pa[i], bv[dt], O[i][dt], 0, 0, 0);
    }

    __syncthreads();   // all P reads done; SH is reused as Osm below

    // stage head-concat tile: Osm[row][h*32 + dt*16 + m]
    #pragma unroll
    for (int i = 0; i < 4; i++)
        #pragma unroll
        for (int dt = 0; dt < 2; dt++)
            #pragma unroll
            for (int rg = 0; rg < 4; rg++)
                Osm[(i*16 + quad*4 + rg)*OSTR + h*Dh + dt*16 + m] =
                    f2bf(O[i][dt][rg]);
    __syncthreads();

    // proj GEMM: 64x128x128; wave h covers out cols [h*32, h*32+32)
    f32x4 pacc[4][2] = {};
    #pragma unroll
    for (int s = 0; s < 4; s++){
        bf16x8 pa[4], pbk[2];
        #pragma unroll
        for (int i = 0; i < 4; i++)
            pa[i] = *(const bf16x8*)&Osm[(i*16 + m)*OSTR + s*32 + quad*8];
        #pragma unroll
        for (int j = 0; j < 2; j++)
            pbk[j] = *(const bf16x8*)&pw[(size_t)(h*Dh + j*16 + m)*Cdim
                                         + s*32 + quad*8];
        #pragma unroll
        for (int i = 0; i < 4; i++)
            #pragma unroll
            for (int j = 0; j < 2; j++)
                pacc[i][j] = __builtin_amdgcn_mfma_f32_16x16x32_bf16(
                                 pa[i], pbk[j], pacc[i][j], 0, 0, 0);
    }
    __syncthreads();   // all Osm reads done

    // stage proj result (+bias) back into Osm
    #pragma unroll
    for (int i = 0; i < 4; i++)
        #pragma unroll
        for (int j = 0; j < 2; j++){
            int c = h*Dh + j*16 + m;
            float bia = pb[c];
            #pragma unroll
            for (int rg = 0; rg < 4; rg++)
                Osm[(i*16 + quad*4 + rg)*OSTR + c] = f2bf(pacc[i][j][rg] + bia);
        }
    __syncthreads();

    // coalesced store: 64 rows x 128 u16 = 1024 chunks of 16 B
    #pragma unroll
    for (int it = 0; it < 4; it++){
        int idx = it*256 + t;
        int r = idx >> 4, c16 = idx & 15;
        *(bf16x8*)&projout[((size_t)w*64 + r)*Cdim + c16*8] =
            *(const bf16x8*)&Osm[r*OSTR + c16*8];
    }
}

extern "C" void kernel_launch(void* const* d_in, const int* in_sizes, int n_in,
                              void* d_out, int out_size, void* d_ws, size_t ws_size,
                              hipStream_t stream) {
    const float* x     = (const float*)d_in[0];
    const float* rpb   = (const float*)d_in[1];
    const float* n1g   = (const float*)d_in[2];
    const float* n1b   = (const float*)d_in[3];
    const float* qkvw  = (const float*)d_in[4];
    const float* qkvb  = (const float*)d_in[5];
    const float* projw = (const float*)d_in[6];
    const float* projb = (const float*)d_in[7];
    const float* n2g   = (const float*)d_in[8];
    const float* n2b   = (const float*)d_in[9];
    const float* fc1w  = (const float*)d_in[10];
    const float* fc1b  = (const float*)d_in[11];
    const float* fc2w  = (const float*)d_in[12];
    const float* fc2b  = (const float*)d_in[13];
    float* out = (float*)d_out;

    if (ws_size < (size_t)230u * 1024u * 1024u) return;

    // Disjoint-lifetime layout (race-free):
    //   region        offset   size   lifetime
    //   projout       0        32M    s2 -> s3
    //   qbuf          32M      32M    s1 -> s2
    //   kbuf          64M      32M    s1 -> s2
    //   vbuf          96M      32M    s1 -> s2
    //   weights/bmt   224M     ~2M    s0 -> end
    char* ws = (char*)d_ws;
    u16*  projout = (u16*)(ws);
    u16*  qbuf    = (u16*)(ws + ((size_t)32  << 20));
    u16*  kbuf    = (u16*)(ws + ((size_t)64  << 20));
    u16*  vbuf    = (u16*)(ws + ((size_t)96  << 20));
    u16*  wb      = (u16*)(ws + ((size_t)224 << 20));
    u16*  qkvw_b  = wb;                // 49152
    u16*  projw_b = wb + 49152;        // 16384
    u16*  fc1w_b  = wb + 65536;        // 65536
    u16*  fc2w_b  = wb + 131072;       // 65536
    float* bmt    = (float*)(ws + ((size_t)225 << 20)); // 256 KiB

    // 0. weight conversions + bias/mask table
    cvt_kernel<<<(49152+255)/256, 256, 0, stream>>>(qkvw, qkvw_b, 49152);
    cvt_kernel<<<(16384+255)/256, 256, 0, stream>>>(projw, projw_b, 16384);
    cvt_kernel<<<(65536+255)/256, 256, 0, stream>>>(fc1w, fc1w_b, 65536);
    cvt_kernel<<<(65536+255)/256, 256, 0, stream>>>(fc2w, fc2w_b, 65536);
    bm_kernel<<<256, 256, 0, stream>>>(rpb, bmt);

    // 1. fused LN1 + QKV GEMM (v staged through LDS for coalesced stores)
    ln1qkv_kernel<<<Mrows/128, 512, 0, stream>>>(
        x, n1g, n1b, qkvw_b, qkvb, qbuf, kbuf, vbuf);
    // 2. fused MFMA windowed attention + proj (block = window)
    attnproj_kernel<<<WTOT, 256, 0, stream>>>(qbuf, kbuf, vbuf, bmt,
                                              projw_b, projb, projout);
    // 3. fused residual + LN2 + MLP -> out (128-row tiles, 512-thr blocks,
    //    16 waves/CU)
    mlp_kernel<<<Mrows/128, 512, 0, stream>>>(
        x, projout, n2g, n2b, fc1w_b, fc1b, fc2w_b, fc2b, out);
}

// Round 11
// 308.833 us; speedup vs baseline: 1.2142x; 1.0642x over previous
//
#include <hip/hip_runtime.h>
#include <math.h>

typedef unsigned short u16;
typedef unsigned int   u32;

#define SS_    4
#define NH     4
#define Dh     32
#define Cdim   128
#define Ntok   64
#define WTOT   2048
#define Mrows  131072   // WTOT * Ntok
#define HIDDEN 512
#define HPAD   136      // LDS row stride (u16): 272 B, 16-B aligned
#define QKSTR  40       // q/k LDS row stride (u16): 80 B, 16-B mult, bank-spread
#define VTSTR  72       // v^T d-row stride (u16): 144 B, 16-B mult
#define PSTR2  72       // P row stride (u16)
#define OSTR   136      // Osm row stride (u16)

// fused-kernel LDS map (u16 offsets), total 38400 u16 = 76800 B -> 2 blocks/CU:
//   Asm/Osm : 0      .. 8704    [64][136]    LN1 tile; reused as Osm in proj
//   Qs      : 8704   .. 18944   [(h*64+n)*40 + d]
//   Ks      : 18944  .. 29184   [(h*64+n)*40 + d]
//   Vs      : 29184  .. 38400   [(h*32+d)*72 + n]
//   Ps      : 8704 (overlay on Qs+Ks after barrier ends all QK^T reads)
#define SH_TOT  38400
#define QOFF    8704
#define KOFF    18944
#define VOFF    29184

typedef __bf16 bf16x8 __attribute__((ext_vector_type(8)));
typedef u16    u16x8  __attribute__((ext_vector_type(8)));
typedef float  f32x4  __attribute__((ext_vector_type(4)));

__device__ __forceinline__ float bf2f(u16 u){
    union {u32 i; float f;} v; v.i = ((u32)u) << 16; return v.f;
}
__device__ __forceinline__ u16 f2bf(float f){
    union {float f; u32 i;} v; v.f = f;
    u32 x = v.i;
    return (u16)((x + 0x7fffu + ((x >> 16) & 1u)) >> 16);
}

// GELU via x*sigmoid(2z) == 0.5x(1+tanh(z)), z = 0.79788456(x+0.044715x^3).
__device__ __forceinline__ float fast_gelu(float v){
    float z = v * (1.5957691216057308f + 0.07135481627561976f * v * v);
    return v / (1.0f + __expf(-z));
}

// token (windowed row) -> original token index (bijection, shift +4 both dims)
__device__ __forceinline__ int map_row_to_token(int r){
    int w = r >> 6, n = r & 63;
    int b = w >> 8, win = w & 255;
    int wy = win >> 4, wx = win & 15;
    int iy = n >> 3, ix = n & 7;
    int ro = (wy*8 + iy + SS_) & 127;
    int co = (wx*8 + ix + SS_) & 127;
    return (b << 14) + (ro << 7) + co;
}

// token index -> windowed row (inverse map)
__device__ __forceinline__ int map_token_to_row(int t){
    int b = t >> 14, ro = (t >> 7) & 127, co = t & 127;
    int y  = (ro + 128 - SS_) & 127;
    int xq = (co + 128 - SS_) & 127;
    return (((b << 8) | ((y >> 3) << 4) | (xq >> 3)) << 6) + (y & 7)*8 + (xq & 7);
}

// ---------------- fp32 -> bf16 weight conversion ----------------
__global__ void __launch_bounds__(256) cvt_kernel(const float* __restrict__ src,
        u16* __restrict__ dst, int n)
{
    int i = blockIdx.x * 256 + threadIdx.x;
    if (i < n) dst[i] = f2bf(src[i]);
}

// ---------------- bias+mask table: bm[cls][h][row][col], 4*4*64*64 fp32 ----------
__global__ void __launch_bounds__(256) bm_kernel(const float* __restrict__ rpb,
        float* __restrict__ bmt)
{
    int e = blockIdx.x * 256 + threadIdx.x;     // 65536 total
    int cls = e >> 14, h = (e >> 12) & 3, row = (e >> 6) & 63, col = e & 63;
    int iy = row >> 3, ix = row & 7, jy = col >> 3, jx = col & 7;
    int bidx = (iy - jy + 7)*15 + (ix - jx + 7);
    float bias = rpb[bidx*NH + h];
    int ybit = cls >> 1, xbit = cls & 1;
    int ri = (ybit ? (iy < 4 ? 1 : 2) : 0)*3 + (xbit ? (ix < 4 ? 1 : 2) : 0);
    int rj = (ybit ? (jy < 4 ? 1 : 2) : 0)*3 + (xbit ? (jx < 4 ? 1 : 2) : 0);
    bmt[e] = bias + ((ri != rj) ? -100.0f : 0.0f);
}

// ==== Fully fused LN1 + QKV + windowed attention + proj, one block = one window.
// q/k/v never touch HBM: QKV GEMM scatters to LDS, attention consumes in-place.
__global__ void __launch_bounds__(256, 2) qkvattn_kernel(
        const float* __restrict__ x,
        const float* __restrict__ g, const float* __restrict__ bsh,
        const u16* __restrict__ Bw,      // qkvw_b [384][128]
        const float* __restrict__ bias,  // qkvb [384]
        const float* __restrict__ bmt,
        const u16* __restrict__ pw, const float* __restrict__ pb,
        u16* __restrict__ projout)
{
    __shared__ __align__(16) u16 SH[SH_TOT];
    u16* Asm = SH;            // [64][HPAD]; later Osm
    u16* Qs  = SH + QOFF;
    u16* Ks  = SH + KOFF;
    u16* Vs  = SH + VOFF;
    u16* Ps  = SH + QOFF;     // overlay (after QK^T barrier)

    int t = threadIdx.x;
    int w = blockIdx.x;
    int win = w & 255;
    int wy = win >> 4, wx = win & 15;
    int cls = ((wy == 15) ? 2 : 0) | ((wx == 15) ? 1 : 0);
    int wv = t >> 6, lane = t & 63;
    int m = lane & 15, quad = lane >> 4;
    size_t tilebase = (size_t)w * 64;

    // ---- phase 1: LN1 stage 64 rows -> Asm ----
    #pragma unroll
    for (int it = 0; it < 4; it++){
        int idx = it*256 + t;
        int rr  = idx >> 4, c8 = idx & 15;
        int src = map_row_to_token((int)tilebase + rr);
        f32x4 xa = *(const f32x4*)&x[(size_t)src*Cdim + c8*8];
        f32x4 xb = *(const f32x4*)&x[(size_t)src*Cdim + c8*8 + 4];
        float s = 0.0f, s2 = 0.0f;
        #pragma unroll
        for (int k = 0; k < 4; k++){
            s += xa[k] + xb[k];
            s2 += xa[k]*xa[k] + xb[k]*xb[k];
        }
        #pragma unroll
        for (int off = 1; off <= 8; off <<= 1){
            s  += __shfl_xor(s,  off, 64);
            s2 += __shfl_xor(s2, off, 64);
        }
        float mean = s * (1.0f/128.0f);
        float var  = s2 * (1.0f/128.0f) - mean*mean;
        float inv  = rsqrtf(var + 1e-5f);
        f32x4 ga = *(const f32x4*)&g[c8*8],  gb = *(const f32x4*)&g[c8*8 + 4];
        f32x4 ba = *(const f32x4*)&bsh[c8*8], bb = *(const f32x4*)&bsh[c8*8 + 4];
        u16x8 ov;
        #pragma unroll
        for (int k = 0; k < 4; k++){
            ov[k]   = f2bf((xa[k] - mean) * inv * ga[k] + ba[k]);
            ov[k+4] = f2bf((xb[k] - mean) * inv * gb[k] + bb[k]);
        }
        *(u16x8*)&Asm[rr*HPAD + c8*8] = ov;
    }
    __syncthreads();

    // ---- phase 2: QKV GEMM, 2 passes x 48 cols/wave; scatter -> LDS ----
    #pragma unroll
    for (int pass = 0; pass < 2; pass++){
        int colbase = pass*192 + wv*48;
        f32x4 acc[4][3] = {};
        #pragma unroll
        for (int s = 0; s < 4; s++){
            bf16x8 aq[4], bk[3];
            #pragma unroll
            for (int i = 0; i < 4; i++)
                aq[i] = *(const bf16x8*)&Asm[(i*16 + m)*HPAD + s*32 + quad*8];
            #pragma unroll
            for (int j = 0; j < 3; j++)
                bk[j] = *(const bf16x8*)&Bw[(size_t)(colbase + j*16 + m)*Cdim
                                            + s*32 + quad*8];
            #pragma unroll
            for (int i = 0; i < 4; i++)
                #pragma unroll
                for (int j = 0; j < 3; j++)
                    acc[i][j] = __builtin_amdgcn_mfma_f32_16x16x32_bf16(
                                    aq[i], bk[j], acc[i][j], 0, 0, 0);
        }
        #pragma unroll
        for (int j = 0; j < 3; j++){
            int c = colbase + j*16 + m;
            float bia = bias[c];
            int which = c >> 7;             // uniform per (pass, wave, j)
            int h = (c >> 5) & 3;
            int d = c & 31;
            #pragma unroll
            for (int i = 0; i < 4; i++){
                #pragma unroll
                for (int rg = 0; rg < 4; rg++){
                    int n = i*16 + quad*4 + rg;
                    float v = acc[i][j][rg] + bia;
                    if (which == 0){
                        Qs[(h*64 + n)*QKSTR + d] = f2bf(v * 0.17677669529663687f);
                    } else if (which == 1){
                        Ks[(h*64 + n)*QKSTR + d] = f2bf(v);
                    } else {
                        Vs[(h*32 + d)*VTSTR + n] = f2bf(v);
                    }
                }
            }
        }
    }
    __syncthreads();   // all q/k/v written; all Asm reads done

    // ---- phase 3: S = Q @ K^T (wave = head) ----
    int h = wv;
    const float* bm = bmt + (size_t)(cls*NH + h)*4096;
    bf16x8 aq[4], bk[4];
    #pragma unroll
    for (int i = 0; i < 4; i++)
        aq[i] = *(const bf16x8*)&Qs[(h*64 + i*16 + m)*QKSTR + quad*8];
    #pragma unroll
    for (int j = 0; j < 4; j++)
        bk[j] = *(const bf16x8*)&Ks[(h*64 + j*16 + m)*QKSTR + quad*8];
    f32x4 S[4][4] = {};
    #pragma unroll
    for (int i = 0; i < 4; i++)
        #pragma unroll
        for (int j = 0; j < 4; j++)
            S[i][j] = __builtin_amdgcn_mfma_f32_16x16x32_bf16(
                          aq[i], bk[j], S[i][j], 0, 0, 0);
    __syncthreads();   // all q/k reads done -> Ps overlay is safe

    // ---- phase 4: softmax -> Ps (wave-private rows; no barrier after) ----
    #pragma unroll
    for (int i = 0; i < 4; i++){
        #pragma unroll
        for (int rg = 0; rg < 4; rg++){
            int row = i*16 + quad*4 + rg;
            float s0 = S[i][0][rg] + bm[row*64 +  0 + m];
            float s1 = S[i][1][rg] + bm[row*64 + 16 + m];
            float s2 = S[i][2][rg] + bm[row*64 + 32 + m];
            float s3 = S[i][3][rg] + bm[row*64 + 48 + m];
            float mx = fmaxf(fmaxf(s0, s1), fmaxf(s2, s3));
            mx = fmaxf(mx, __shfl_xor(mx, 1, 64));
            mx = fmaxf(mx, __shfl_xor(mx, 2, 64));
            mx = fmaxf(mx, __shfl_xor(mx, 4, 64));
            mx = fmaxf(mx, __shfl_xor(mx, 8, 64));
            s0 = __expf(s0 - mx); s1 = __expf(s1 - mx);
            s2 = __expf(s2 - mx); s3 = __expf(s3 - mx);
            float sm = s0 + s1 + s2 + s3;
            sm += __shfl_xor(sm, 1, 64);
            sm += __shfl_xor(sm, 2, 64);
            sm += __shfl_xor(sm, 4, 64);
            sm += __shfl_xor(sm, 8, 64);
            float rinv = 1.0f / sm;
            u16* pr = &Ps[(h*64 + row)*PSTR2];
            pr[ 0 + m] = f2bf(s0 * rinv);
            pr[16 + m] = f2bf(s1 * rinv);
            pr[32 + m] = f2bf(s2 * rinv);
            pr[48 + m] = f2bf(s3 * rinv);
        }
    }

    // ---- phase 5: O = P @ V (own-wave P rows; Vs stable since phase 2) ----
    f32x4 O[4][2] = {};
    #pragma unroll
    for (int s2 = 0; s2 < 2; s2++){
        bf16x8 pa[4], bv[2];
        #pragma unroll
        for (int i = 0; i < 4; i++)
            pa[i] = *(const bf16x8*)&Ps[(h*64 + i*16 + m)*PSTR2 + s2*32 + quad*8];
        #pragma unroll
        for (int dt = 0; dt < 2; dt++)
            bv[dt] = *(const bf16x8*)&Vs[(h*32 + dt*16 + m)*VTSTR + s2*32 + quad*8];
        #pragma unroll
        for (int i = 0; i < 4; i++)
            #pragma unroll
            for (int dt = 0; dt < 2; dt++)
                O[i][dt] = __builtin_amdgcn_mfma_f32_16x16x32_bf16(
                               pa[i], bv[dt], O[i][dt], 0, 0, 0);
    }

    // ---- phase 6: stage head-concat O -> Osm (Asm region, dead since ph.2) ----
    u16* Osm = Asm;
    #pragma unroll
    for (int i = 0; i < 4; i++)
        #pragma unroll
        for (int dt = 0; dt < 2; dt++)
            #pragma unroll
            for (int rg = 0; rg < 4; rg++)
                Osm[(i*16 + quad*4 + rg)*OSTR + h*Dh + dt*16 + m] =
                    f2bf(O[i][dt][rg]);
    __syncthreads();

    // ---- phase 7: proj GEMM (wave h -> out cols h*32..+32) ----
    f32x4 pacc[4][2] = {};
    #pragma unroll
    for (int s = 0; s < 4; s++){
        bf16x8 pa[4], pbk[2];
        #pragma unroll
        for (int i = 0; i < 4; i++)
            pa[i] = *(const bf16x8*)&Osm[(i*16 + m)*OSTR + s*32 + quad*8];
        #pragma unroll
        for (int j = 0; j < 2; j++)
            pbk[j] = *(const bf16x8*)&pw[(size_t)(h*Dh + j*16 + m)*Cdim
                                         + s*32 + quad*8];
        #pragma unroll
        for (int i = 0; i < 4; i++)
            #pragma unroll
            for (int j = 0; j < 2; j++)
                pacc[i][j] = __builtin_amdgcn_mfma_f32_16x16x32_bf16(
                                 pa[i], pbk[j], pacc[i][j], 0, 0, 0);
    }
    __syncthreads();   // all Osm reads done

    #pragma unroll
    for (int i = 0; i < 4; i++)
        #pragma unroll
        for (int j = 0; j < 2; j++){
            int c = h*Dh + j*16 + m;
            float bia = pb[c];
            #pragma unroll
            for (int rg = 0; rg < 4; rg++)
                Osm[(i*16 + quad*4 + rg)*OSTR + c] = f2bf(pacc[i][j][rg] + bia);
        }
    __syncthreads();

    // ---- phase 8: coalesced projout store (64 rows x 128 = 1024 x 16 B) ----
    #pragma unroll
    for (int it = 0; it < 4; it++){
        int idx = it*256 + t;
        int r = idx >> 4, c16 = idx & 15;
        *(bf16x8*)&projout[(tilebase + r)*Cdim + c16*8] =
            *(const bf16x8*)&Osm[r*OSTR + c16*8];
    }
}

// --- Fused residual + LN2 + MLP, 512-thread blocks (8 waves 2x4):
// 128-row tile, 2 blocks/CU (16 waves/CU), weights L2-resident.
__global__ void __launch_bounds__(512, 4) mlp_kernel(
        const float* __restrict__ x,     // [Mrows][128] fp32, token order
        const u16* __restrict__ projout, // [Mrows][128] bf16, windowed order
        const float* __restrict__ g, const float* __restrict__ bsh,
        const u16* __restrict__ W1,      // fc1w [512][128] bf16
        const float* __restrict__ b1,
        const u16* __restrict__ W2,      // fc2w [128][512] bf16
        const float* __restrict__ b2,
        float* __restrict__ outp)        // out  [Mrows][128] fp32
{
    __shared__ __align__(16) u16 Asm[128*HPAD];
    __shared__ __align__(16) u16 Hsm[128*HPAD];
    int t = threadIdx.x;
    int wave = t >> 6, lane = t & 63;
    int wr = wave & 1, wc = wave >> 1;           // wr: 0..1 (rows), wc: 0..3 (cols)
    int m = lane & 15, quad = lane >> 4;
    size_t rowbase = (size_t)blockIdx.x * 128;

    // ---- fused stage: val = x + proj~, LN2 -> bf16 Asm tile ----
    #pragma unroll
    for (int it = 0; it < 4; it++){
        int idx  = it*512 + t;
        int r    = idx >> 4, c8 = idx & 15;
        int trow = (int)rowbase + r;
        int rr   = map_token_to_row(trow);
        f32x4 xa = *(const f32x4*)&x[(size_t)trow*Cdim + c8*8];
        f32x4 xb = *(const f32x4*)&x[(size_t)trow*Cdim + c8*8 + 4];
        u16x8 pv = *(const u16x8*)&projout[(size_t)rr*Cdim + c8*8];
        float val[8];
        float s = 0.0f, s2 = 0.0f;
        #pragma unroll
        for (int k = 0; k < 8; k++){
            float xv = (k < 4) ? xa[k] : xb[k-4];
            val[k] = xv + bf2f(pv[k]);
            s += val[k]; s2 += val[k]*val[k];
        }
        #pragma unroll
        for (int off = 1; off <= 8; off <<= 1){
            s  += __shfl_xor(s,  off, 64);
            s2 += __shfl_xor(s2, off, 64);
        }
        float mean = s * (1.0f/128.0f);
        float var  = s2 * (1.0f/128.0f) - mean*mean;
        float inv  = rsqrtf(var + 1e-5f);
        f32x4 ga = *(const f32x4*)&g[c8*8],  gb = *(const f32x4*)&g[c8*8 + 4];
        f32x4 ba = *(const f32x4*)&bsh[c8*8], bb = *(const f32x4*)&bsh[c8*8 + 4];
        u16x8 ov;
        #pragma unroll
        for (int k = 0; k < 8; k++){
            float gv = (k < 4) ? ga[k] : gb[k-4];
            float bv = (k < 4) ? ba[k] : bb[k-4];
            ov[k] = f2bf((val[k] - mean) * inv * gv + bv);
        }
        *(u16x8*)&Asm[r*HPAD + c8*8] = ov;
    }
    __syncthreads();

    f32x4 O[4][2] = {};                  // 64 rows x 32 out cols per wave

    for (int kk = 0; kk < 4; kk++){
        // ---- H chunk: wave (wr,wc) computes rows wr*64..+64, hid cols wc*32..+32
        f32x4 Hacc[4][2] = {};
        #pragma unroll
        for (int s = 0; s < 4; s++){
            bf16x8 aq[4], bk[2];
            #pragma unroll
            for (int i = 0; i < 4; i++)
                aq[i] = *(const bf16x8*)&Asm[(wr*64 + i*16 + m)*HPAD + s*32 + quad*8];
            #pragma unroll
            for (int j = 0; j < 2; j++)
                bk[j] = *(const bf16x8*)&W1[(size_t)(kk*128 + wc*32 + j*16 + m)*Cdim
                                            + s*32 + quad*8];
            #pragma unroll
            for (int i = 0; i < 4; i++)
                #pragma unroll
                for (int j = 0; j < 2; j++)
                    Hacc[i][j] = __builtin_amdgcn_mfma_f32_16x16x32_bf16(
                                     aq[i], bk[j], Hacc[i][j], 0, 0, 0);
        }
        #pragma unroll
        for (int i = 0; i < 4; i++){
            #pragma unroll
            for (int j = 0; j < 2; j++){
                int hc = wc*32 + j*16 + m;          // hidden col within chunk
                float bia = b1[kk*128 + hc];
                #pragma unroll
                for (int rg = 0; rg < 4; rg++){
                    int r = wr*64 + i*16 + quad*4 + rg;
                    Hsm[r*HPAD + hc] = f2bf(fast_gelu(Hacc[i][j][rg] + bia));
                }
            }
        }
        __syncthreads();

        // ---- O += Hc @ W2[:, kk*128 ..]^T  (out cols wc*32..+32) ----
        #pragma unroll
        for (int s = 0; s < 4; s++){
            bf16x8 pa[4], bk[2];
            #pragma unroll
            for (int i = 0; i < 4; i++)
                pa[i] = *(const bf16x8*)&Hsm[(wr*64 + i*16 + m)*HPAD + s*32 + quad*8];
            #pragma unroll
            for (int j = 0; j < 2; j++)
                bk[j] = *(const bf16x8*)&W2[(size_t)(wc*32 + j*16 + m)*HIDDEN
                                            + kk*128 + s*32 + quad*8];
            #pragma unroll
            for (int i = 0; i < 4; i++)
                #pragma unroll
                for (int j = 0; j < 2; j++)
                    O[i][j] = __builtin_amdgcn_mfma_f32_16x16x32_bf16(
                                  pa[i], bk[j], O[i][j], 0, 0, 0);
        }
        __syncthreads();   // Hsm reused next chunk
    }

    // ---- epilogue: out = (x + proj~) + O + b2 (x/proj re-read; L2-hot) ----
    #pragma unroll
    for (int i = 0; i < 4; i++){
        #pragma unroll
        for (int rg = 0; rg < 4; rg++){
            int r  = (int)rowbase + wr*64 + i*16 + quad*4 + rg;   // token row
            int rr = map_token_to_row(r);
            #pragma unroll
            for (int j = 0; j < 2; j++){
                int c = wc*32 + j*16 + m;
                float v = x[(size_t)r*Cdim + c] + bf2f(projout[(size_t)rr*Cdim + c])
                          + O[i][j][rg] + b2[c];
                outp[(size_t)r*Cdim + c] = v;
            }
        }
    }
}

extern "C" void kernel_launch(void* const* d_in, const int* in_sizes, int n_in,
                              void* d_out, int out_size, void* d_ws, size_t ws_size,
                              hipStream_t stream) {
    const float* x     = (const float*)d_in[0];
    const float* rpb   = (const float*)d_in[1];
    const float* n1g   = (const float*)d_in[2];
    const float* n1b   = (const float*)d_in[3];
    const float* qkvw  = (const float*)d_in[4];
    const float* qkvb  = (const float*)d_in[5];
    const float* projw = (const float*)d_in[6];
    const float* projb = (const float*)d_in[7];
    const float* n2g   = (const float*)d_in[8];
    const float* n2b   = (const float*)d_in[9];
    const float* fc1w  = (const float*)d_in[10];
    const float* fc1b  = (const float*)d_in[11];
    const float* fc2w  = (const float*)d_in[12];
    const float* fc2b  = (const float*)d_in[13];
    float* out = (float*)d_out;

    if (ws_size < (size_t)230u * 1024u * 1024u) return;

    // Workspace layout:
    //   projout       0        32M    s1 -> s2
    //   weights/bmt   224M     ~2M    s0 -> end
    char* ws = (char*)d_ws;
    u16*  projout = (u16*)(ws);
    u16*  wb      = (u16*)(ws + ((size_t)224 << 20));
    u16*  qkvw_b  = wb;                // 49152
    u16*  projw_b = wb + 49152;        // 16384
    u16*  fc1w_b  = wb + 65536;        // 65536
    u16*  fc2w_b  = wb + 131072;       // 65536
    float* bmt    = (float*)(ws + ((size_t)225 << 20)); // 256 KiB

    // 0. weight conversions + bias/mask table
    cvt_kernel<<<(49152+255)/256, 256, 0, stream>>>(qkvw, qkvw_b, 49152);
    cvt_kernel<<<(16384+255)/256, 256, 0, stream>>>(projw, projw_b, 16384);
    cvt_kernel<<<(65536+255)/256, 256, 0, stream>>>(fc1w, fc1w_b, 65536);
    cvt_kernel<<<(65536+255)/256, 256, 0, stream>>>(fc2w, fc2w_b, 65536);
    bm_kernel<<<256, 256, 0, stream>>>(rpb, bmt);

    // 1. fully fused LN1 + QKV + attention + proj (block = window; qkv in LDS)
    qkvattn_kernel<<<WTOT, 256, 0, stream>>>(
        x, n1g, n1b, qkvw_b, qkvb, bmt, projw_b, projb, projout);
    // 2. fused residual + LN2 + MLP -> out
    mlp_kernel<<<Mrows/128, 512, 0, stream>>>(
        x, projout, n2g, n2b, fc1w_b, fc1b, fc2w_b, fc2b, out);
}

// Round 12
// 305.803 us; speedup vs baseline: 1.2262x; 1.0099x over previous
//
#include <hip/hip_runtime.h>
#include <math.h>

typedef unsigned short u16;
typedef unsigned int   u32;

#define SS_    4
#define NH     4
#define Dh     32
#define Cdim   128
#define Ntok   64
#define WTOT   2048
#define Mrows  131072   // WTOT * Ntok
#define HIDDEN 512
#define HPAD   136      // LDS row stride (u16): 272 B, 16-B aligned
#define QKSTR  40       // q/k LDS row stride (u16): 80 B, 16-B mult, bank-spread
#define VTSTR  72       // v^T d-row stride (u16): 144 B, 16-B mult
#define PSTR2  72       // P row stride (u16)
#define OSTR   136      // Osm row stride (u16)

// fused-kernel LDS map (u16 offsets), total 38400 u16 = 76800 B -> 2 blocks/CU:
//   Asm/Osm : 0      .. 8704    [64][136]    LN1 tile; reused as Osm in proj
//   Qs      : 8704   .. 18944   [(h*64+n)*40 + d]
//   Ks      : 18944  .. 29184   [(h*64+n)*40 + d]
//   Vs      : 29184  .. 38400   [(h*32+d)*72 + n]
//   Ps      : 8704 (overlay on Qs+Ks after barrier ends all QK^T reads)
#define SH_TOT  38400
#define QOFF    8704
#define KOFF    18944
#define VOFF    29184

typedef __bf16 bf16x8 __attribute__((ext_vector_type(8)));
typedef u16    u16x8  __attribute__((ext_vector_type(8)));
typedef float  f32x4  __attribute__((ext_vector_type(4)));

__device__ __forceinline__ float bf2f(u16 u){
    union {u32 i; float f;} v; v.i = ((u32)u) << 16; return v.f;
}
__device__ __forceinline__ u16 f2bf(float f){
    union {float f; u32 i;} v; v.f = f;
    u32 x = v.i;
    return (u16)((x + 0x7fffu + ((x >> 16) & 1u)) >> 16);
}

// GELU via x*sigmoid(2z) == 0.5x(1+tanh(z)), z = 0.79788456(x+0.044715x^3).
__device__ __forceinline__ float fast_gelu(float v){
    float z = v * (1.5957691216057308f + 0.07135481627561976f * v * v);
    return v / (1.0f + __expf(-z));
}

// token (windowed row) -> original token index (bijection, shift +4 both dims)
__device__ __forceinline__ int map_row_to_token(int r){
    int w = r >> 6, n = r & 63;
    int b = w >> 8, win = w & 255;
    int wy = win >> 4, wx = win & 15;
    int iy = n >> 3, ix = n & 7;
    int ro = (wy*8 + iy + SS_) & 127;
    int co = (wx*8 + ix + SS_) & 127;
    return (b << 14) + (ro << 7) + co;
}

// token index -> windowed row (inverse map)
__device__ __forceinline__ int map_token_to_row(int t){
    int b = t >> 14, ro = (t >> 7) & 127, co = t & 127;
    int y  = (ro + 128 - SS_) & 127;
    int xq = (co + 128 - SS_) & 127;
    return (((b << 8) | ((y >> 3) << 4) | (xq >> 3)) << 6) + (y & 7)*8 + (xq & 7);
}

// ---------------- fp32 -> bf16 weight conversion ----------------
__global__ void __launch_bounds__(256) cvt_kernel(const float* __restrict__ src,
        u16* __restrict__ dst, int n)
{
    int i = blockIdx.x * 256 + threadIdx.x;
    if (i < n) dst[i] = f2bf(src[i]);
}

// ---------------- bias+mask table: bm[cls][h][row][col], 4*4*64*64 fp32 ----------
__global__ void __launch_bounds__(256) bm_kernel(const float* __restrict__ rpb,
        float* __restrict__ bmt)
{
    int e = blockIdx.x * 256 + threadIdx.x;     // 65536 total
    int cls = e >> 14, h = (e >> 12) & 3, row = (e >> 6) & 63, col = e & 63;
    int iy = row >> 3, ix = row & 7, jy = col >> 3, jx = col & 7;
    int bidx = (iy - jy + 7)*15 + (ix - jx + 7);
    float bias = rpb[bidx*NH + h];
    int ybit = cls >> 1, xbit = cls & 1;
    int ri = (ybit ? (iy < 4 ? 1 : 2) : 0)*3 + (xbit ? (ix < 4 ? 1 : 2) : 0);
    int rj = (ybit ? (jy < 4 ? 1 : 2) : 0)*3 + (xbit ? (jx < 4 ? 1 : 2) : 0);
    bmt[e] = bias + ((ri != rj) ? -100.0f : 0.0f);
}

// ==== Fully fused LN1 + QKV + windowed attention + proj, one block = one window.
// 512 threads (8 waves): QKV = 48 cols/wave single pass; attention = 2 waves
// per head (32 rows each); proj = (row-half x 4 col-groups). Same LDS (76.8 KB,
// 2 blocks/CU) but 16 waves/CU instead of 8 -> double latency hiding.
__global__ void __launch_bounds__(512, 4) qkvattn_kernel(
        const float* __restrict__ x,
        const float* __restrict__ g, const float* __restrict__ bsh,
        const u16* __restrict__ Bw,      // qkvw_b [384][128]
        const float* __restrict__ bias,  // qkvb [384]
        const float* __restrict__ bmt,
        const u16* __restrict__ pw, const float* __restrict__ pb,
        u16* __restrict__ projout)
{
    __shared__ __align__(16) u16 SH[SH_TOT];
    u16* Asm = SH;            // [64][HPAD]; later Osm
    u16* Qs  = SH + QOFF;
    u16* Ks  = SH + KOFF;
    u16* Vs  = SH + VOFF;
    u16* Ps  = SH + QOFF;     // overlay (after QK^T barrier)

    int t = threadIdx.x;
    int w = blockIdx.x;
    int win = w & 255;
    int wy = win >> 4, wx = win & 15;
    int cls = ((wy == 15) ? 2 : 0) | ((wx == 15) ? 1 : 0);
    int wv = t >> 6, lane = t & 63;
    int m = lane & 15, quad = lane >> 4;
    size_t tilebase = (size_t)w * 64;

    // ---- phase 1: LN1 stage 64 rows -> Asm (1024 chunks of 16 B) ----
    #pragma unroll
    for (int it = 0; it < 2; it++){
        int idx = it*512 + t;
        int rr  = idx >> 4, c8 = idx & 15;
        int src = map_row_to_token((int)tilebase + rr);
        f32x4 xa = *(const f32x4*)&x[(size_t)src*Cdim + c8*8];
        f32x4 xb = *(const f32x4*)&x[(size_t)src*Cdim + c8*8 + 4];
        float s = 0.0f, s2 = 0.0f;
        #pragma unroll
        for (int k = 0; k < 4; k++){
            s += xa[k] + xb[k];
            s2 += xa[k]*xa[k] + xb[k]*xb[k];
        }
        #pragma unroll
        for (int off = 1; off <= 8; off <<= 1){
            s  += __shfl_xor(s,  off, 64);
            s2 += __shfl_xor(s2, off, 64);
        }
        float mean = s * (1.0f/128.0f);
        float var  = s2 * (1.0f/128.0f) - mean*mean;
        float inv  = rsqrtf(var + 1e-5f);
        f32x4 ga = *(const f32x4*)&g[c8*8],  gb = *(const f32x4*)&g[c8*8 + 4];
        f32x4 ba = *(const f32x4*)&bsh[c8*8], bb = *(const f32x4*)&bsh[c8*8 + 4];
        u16x8 ov;
        #pragma unroll
        for (int k = 0; k < 4; k++){
            ov[k]   = f2bf((xa[k] - mean) * inv * ga[k] + ba[k]);
            ov[k+4] = f2bf((xb[k] - mean) * inv * gb[k] + bb[k]);
        }
        *(u16x8*)&Asm[rr*HPAD + c8*8] = ov;
    }
    __syncthreads();

    // ---- phase 2: QKV GEMM, one pass, 48 cols/wave; scatter -> LDS ----
    {
        int colbase = wv*48;
        f32x4 acc[4][3] = {};
        #pragma unroll
        for (int s = 0; s < 4; s++){
            bf16x8 aq[4], bk[3];
            #pragma unroll
            for (int i = 0; i < 4; i++)
                aq[i] = *(const bf16x8*)&Asm[(i*16 + m)*HPAD + s*32 + quad*8];
            #pragma unroll
            for (int j = 0; j < 3; j++)
                bk[j] = *(const bf16x8*)&Bw[(size_t)(colbase + j*16 + m)*Cdim
                                            + s*32 + quad*8];
            #pragma unroll
            for (int i = 0; i < 4; i++)
                #pragma unroll
                for (int j = 0; j < 3; j++)
                    acc[i][j] = __builtin_amdgcn_mfma_f32_16x16x32_bf16(
                                    aq[i], bk[j], acc[i][j], 0, 0, 0);
        }
        #pragma unroll
        for (int j = 0; j < 3; j++){
            int c = colbase + j*16 + m;
            float bia = bias[c];
            int which = c >> 7;             // uniform per (wave, j): 16-col chunk
            int h = (c >> 5) & 3;
            int d = c & 31;
            #pragma unroll
            for (int i = 0; i < 4; i++){
                #pragma unroll
                for (int rg = 0; rg < 4; rg++){
                    int n = i*16 + quad*4 + rg;
                    float v = acc[i][j][rg] + bia;
                    if (which == 0){
                        Qs[(h*64 + n)*QKSTR + d] = f2bf(v * 0.17677669529663687f);
                    } else if (which == 1){
                        Ks[(h*64 + n)*QKSTR + d] = f2bf(v);
                    } else {
                        Vs[(h*32 + d)*VTSTR + n] = f2bf(v);
                    }
                }
            }
        }
    }
    __syncthreads();   // all q/k/v written; all Asm reads done

    // ---- phase 3: S = Q @ K^T (wave = (head, row-half), 32 rows each) ----
    int h = wv >> 1, half = wv & 1;
    const float* bm = bmt + (size_t)(cls*NH + h)*4096;
    bf16x8 aq[2], bk[4];
    #pragma unroll
    for (int i = 0; i < 2; i++)
        aq[i] = *(const bf16x8*)&Qs[(h*64 + half*32 + i*16 + m)*QKSTR + quad*8];
    #pragma unroll
    for (int j = 0; j < 4; j++)
        bk[j] = *(const bf16x8*)&Ks[(h*64 + j*16 + m)*QKSTR + quad*8];
    f32x4 S[2][4] = {};
    #pragma unroll
    for (int i = 0; i < 2; i++)
        #pragma unroll
        for (int j = 0; j < 4; j++)
            S[i][j] = __builtin_amdgcn_mfma_f32_16x16x32_bf16(
                          aq[i], bk[j], S[i][j], 0, 0, 0);
    __syncthreads();   // all q/k reads done -> Ps overlay is safe

    // ---- phase 4: softmax -> Ps (wave-private rows; no barrier after) ----
    #pragma unroll
    for (int i = 0; i < 2; i++){
        #pragma unroll
        for (int rg = 0; rg < 4; rg++){
            int row = half*32 + i*16 + quad*4 + rg;
            float s0 = S[i][0][rg] + bm[row*64 +  0 + m];
            float s1 = S[i][1][rg] + bm[row*64 + 16 + m];
            float s2 = S[i][2][rg] + bm[row*64 + 32 + m];
            float s3 = S[i][3][rg] + bm[row*64 + 48 + m];
            float mx = fmaxf(fmaxf(s0, s1), fmaxf(s2, s3));
            mx = fmaxf(mx, __shfl_xor(mx, 1, 64));
            mx = fmaxf(mx, __shfl_xor(mx, 2, 64));
            mx = fmaxf(mx, __shfl_xor(mx, 4, 64));
            mx = fmaxf(mx, __shfl_xor(mx, 8, 64));
            s0 = __expf(s0 - mx); s1 = __expf(s1 - mx);
            s2 = __expf(s2 - mx); s3 = __expf(s3 - mx);
            float sm = s0 + s1 + s2 + s3;
            sm += __shfl_xor(sm, 1, 64);
            sm += __shfl_xor(sm, 2, 64);
            sm += __shfl_xor(sm, 4, 64);
            sm += __shfl_xor(sm, 8, 64);
            float rinv = 1.0f / sm;
            u16* pr = &Ps[(h*64 + row)*PSTR2];
            pr[ 0 + m] = f2bf(s0 * rinv);
            pr[16 + m] = f2bf(s1 * rinv);
            pr[32 + m] = f2bf(s2 * rinv);
            pr[48 + m] = f2bf(s3 * rinv);
        }
    }

    // ---- phase 5: O = P @ V (own-wave P rows; Vs stable since phase 2) ----
    f32x4 O[2][2] = {};
    #pragma unroll
    for (int s2 = 0; s2 < 2; s2++){
        bf16x8 pa[2], bv[2];
        #pragma unroll
        for (int i = 0; i < 2; i++)
            pa[i] = *(const bf16x8*)&Ps[(h*64 + half*32 + i*16 + m)*PSTR2
                                        + s2*32 + quad*8];
        #pragma unroll
        for (int dt = 0; dt < 2; dt++)
            bv[dt] = *(const bf16x8*)&Vs[(h*32 + dt*16 + m)*VTSTR + s2*32 + quad*8];
        #pragma unroll
        for (int i = 0; i < 2; i++)
            #pragma unroll
            for (int dt = 0; dt < 2; dt++)
                O[i][dt] = __builtin_amdgcn_mfma_f32_16x16x32_bf16(
                               pa[i], bv[dt], O[i][dt], 0, 0, 0);
    }

    // ---- phase 6: stage head-concat O -> Osm (Asm region, dead since ph.2) ----
    u16* Osm = Asm;
    #pragma unroll
    for (int i = 0; i < 2; i++)
        #pragma unroll
        for (int dt = 0; dt < 2; dt++)
            #pragma unroll
            for (int rg = 0; rg < 4; rg++)
                Osm[(half*32 + i*16 + quad*4 + rg)*OSTR + h*Dh + dt*16 + m] =
                    f2bf(O[i][dt][rg]);
    __syncthreads();

    // ---- phase 7: proj GEMM (wave = (row-half, col-group of 32)) ----
    int rh = wv & 1, cg = wv >> 1;
    f32x4 pacc[2][2] = {};
    #pragma unroll
    for (int s = 0; s < 4; s++){
        bf16x8 pa[2], pbk[2];
        #pragma unroll
        for (int i = 0; i < 2; i++)
            pa[i] = *(const bf16x8*)&Osm[(rh*32 + i*16 + m)*OSTR + s*32 + quad*8];
        #pragma unroll
        for (int j = 0; j < 2; j++)
            pbk[j] = *(const bf16x8*)&pw[(size_t)(cg*32 + j*16 + m)*Cdim
                                         + s*32 + quad*8];
        #pragma unroll
        for (int i = 0; i < 2; i++)
            #pragma unroll
            for (int j = 0; j < 2; j++)
                pacc[i][j] = __builtin_amdgcn_mfma_f32_16x16x32_bf16(
                                 pa[i], pbk[j], pacc[i][j], 0, 0, 0);
    }
    __syncthreads();   // all Osm reads done

    #pragma unroll
    for (int i = 0; i < 2; i++)
        #pragma unroll
        for (int j = 0; j < 2; j++){
            int c = cg*32 + j*16 + m;
            float bia = pb[c];
            #pragma unroll
            for (int rg = 0; rg < 4; rg++)
                Osm[(rh*32 + i*16 + quad*4 + rg)*OSTR + c] =
                    f2bf(pacc[i][j][rg] + bia);
        }
    __syncthreads();

    // ---- phase 8: coalesced projout store (64 rows x 128 = 1024 x 16 B) ----
    #pragma unroll
    for (int it = 0; it < 2; it++){
        int idx = it*512 + t;
        int r = idx >> 4, c16 = idx & 15;
        *(bf16x8*)&projout[(tilebase + r)*Cdim + c16*8] =
            *(const bf16x8*)&Osm[r*OSTR + c16*8];
    }
}

// --- Fused residual + LN2 + MLP, 512-thread blocks (8 waves 2x4):
// 128-row tile, 2 blocks/CU (16 waves/CU), weights L2-resident.
__global__ void __launch_bounds__(512, 4) mlp_kernel(
        const float* __restrict__ x,     // [Mrows][128] fp32, token order
        const u16* __restrict__ projout, // [Mrows][128] bf16, windowed order
        const float* __restrict__ g, const float* __restrict__ bsh,
        const u16* __restrict__ W1,      // fc1w [512][128] bf16
        const float* __restrict__ b1,
        const u16* __restrict__ W2,      // fc2w [128][512] bf16
        const float* __restrict__ b2,
        float* __restrict__ outp)        // out  [Mrows][128] fp32
{
    __shared__ __align__(16) u16 Asm[128*HPAD];
    __shared__ __align__(16) u16 Hsm[128*HPAD];
    int t = threadIdx.x;
    int wave = t >> 6, lane = t & 63;
    int wr = wave & 1, wc = wave >> 1;           // wr: 0..1 (rows), wc: 0..3 (cols)
    int m = lane & 15, quad = lane >> 4;
    size_t rowbase = (size_t)blockIdx.x * 128;

    // ---- fused stage: val = x + proj~, LN2 -> bf16 Asm tile ----
    #pragma unroll
    for (int it = 0; it < 4; it++){
        int idx  = it*512 + t;
        int r    = idx >> 4, c8 = idx & 15;
        int trow = (int)rowbase + r;
        int rr   = map_token_to_row(trow);
        f32x4 xa = *(const f32x4*)&x[(size_t)trow*Cdim + c8*8];
        f32x4 xb = *(const f32x4*)&x[(size_t)trow*Cdim + c8*8 + 4];
        u16x8 pv = *(const u16x8*)&projout[(size_t)rr*Cdim + c8*8];
        float val[8];
        float s = 0.0f, s2 = 0.0f;
        #pragma unroll
        for (int k = 0; k < 8; k++){
            float xv = (k < 4) ? xa[k] : xb[k-4];
            val[k] = xv + bf2f(pv[k]);
            s += val[k]; s2 += val[k]*val[k];
        }
        #pragma unroll
        for (int off = 1; off <= 8; off <<= 1){
            s  += __shfl_xor(s,  off, 64);
            s2 += __shfl_xor(s2, off, 64);
        }
        float mean = s * (1.0f/128.0f);
        float var  = s2 * (1.0f/128.0f) - mean*mean;
        float inv  = rsqrtf(var + 1e-5f);
        f32x4 ga = *(const f32x4*)&g[c8*8],  gb = *(const f32x4*)&g[c8*8 + 4];
        f32x4 ba = *(const f32x4*)&bsh[c8*8], bb = *(const f32x4*)&bsh[c8*8 + 4];
        u16x8 ov;
        #pragma unroll
        for (int k = 0; k < 8; k++){
            float gv = (k < 4) ? ga[k] : gb[k-4];
            float bv = (k < 4) ? ba[k] : bb[k-4];
            ov[k] = f2bf((val[k] - mean) * inv * gv + bv);
        }
        *(u16x8*)&Asm[r*HPAD + c8*8] = ov;
    }
    __syncthreads();

    f32x4 O[4][2] = {};                  // 64 rows x 32 out cols per wave

    for (int kk = 0; kk < 4; kk++){
        // ---- H chunk: wave (wr,wc) computes rows wr*64..+64, hid cols wc*32..+32
        f32x4 Hacc[4][2] = {};
        #pragma unroll
        for (int s = 0; s < 4; s++){
            bf16x8 aq[4], bk[2];
            #pragma unroll
            for (int i = 0; i < 4; i++)
                aq[i] = *(const bf16x8*)&Asm[(wr*64 + i*16 + m)*HPAD + s*32 + quad*8];
            #pragma unroll
            for (int j = 0; j < 2; j++)
                bk[j] = *(const bf16x8*)&W1[(size_t)(kk*128 + wc*32 + j*16 + m)*Cdim
                                            + s*32 + quad*8];
            #pragma unroll
            for (int i = 0; i < 4; i++)
                #pragma unroll
                for (int j = 0; j < 2; j++)
                    Hacc[i][j] = __builtin_amdgcn_mfma_f32_16x16x32_bf16(
                                     aq[i], bk[j], Hacc[i][j], 0, 0, 0);
        }
        #pragma unroll
        for (int i = 0; i < 4; i++){
            #pragma unroll
            for (int j = 0; j < 2; j++){
                int hc = wc*32 + j*16 + m;          // hidden col within chunk
                float bia = b1[kk*128 + hc];
                #pragma unroll
                for (int rg = 0; rg < 4; rg++){
                    int r = wr*64 + i*16 + quad*4 + rg;
                    Hsm[r*HPAD + hc] = f2bf(fast_gelu(Hacc[i][j][rg] + bia));
                }
            }
        }
        __syncthreads();

        // ---- O += Hc @ W2[:, kk*128 ..]^T  (out cols wc*32..+32) ----
        #pragma unroll
        for (int s = 0; s < 4; s++){
            bf16x8 pa[4], bk[2];
            #pragma unroll
            for (int i = 0; i < 4; i++)
                pa[i] = *(const bf16x8*)&Hsm[(wr*64 + i*16 + m)*HPAD + s*32 + quad*8];
            #pragma unroll
            for (int j = 0; j < 2; j++)
                bk[j] = *(const bf16x8*)&W2[(size_t)(wc*32 + j*16 + m)*HIDDEN
                                            + kk*128 + s*32 + quad*8];
            #pragma unroll
            for (int i = 0; i < 4; i++)
                #pragma unroll
                for (int j = 0; j < 2; j++)
                    O[i][j] = __builtin_amdgcn_mfma_f32_16x16x32_bf16(
                                  pa[i], bk[j], O[i][j], 0, 0, 0);
        }
        __syncthreads();   // Hsm reused next chunk
    }

    // ---- epilogue: out = (x + proj~) + O + b2 (x/proj re-read; L2-hot) ----
    #pragma unroll
    for (int i = 0; i < 4; i++){
        #pragma unroll
        for (int rg = 0; rg < 4; rg++){
            int r  = (int)rowbase + wr*64 + i*16 + quad*4 + rg;   // token row
            int rr = map_token_to_row(r);
            #pragma unroll
            for (int j = 0; j < 2; j++){
                int c = wc*32 + j*16 + m;
                float v = x[(size_t)r*Cdim + c] + bf2f(projout[(size_t)rr*Cdim + c])
                          + O[i][j][rg] + b2[c];
                outp[(size_t)r*Cdim + c] = v;
            }
        }
    }
}

extern "C" void kernel_launch(void* const* d_in, const int* in_sizes, int n_in,
                              void* d_out, int out_size, void* d_ws, size_t ws_size,
                              hipStream_t stream) {
    const float* x     = (const float*)d_in[0];
    const float* rpb   = (const float*)d_in[1];
    const float* n1g   = (const float*)d_in[2];
    const float* n1b   = (const float*)d_in[3];
    const float* qkvw  = (const float*)d_in[4];
    const float* qkvb  = (const float*)d_in[5];
    const float* projw = (const float*)d_in[6];
    const float* projb = (const float*)d_in[7];
    const float* n2g   = (const float*)d_in[8];
    const float* n2b   = (const float*)d_in[9];
    const float* fc1w  = (const float*)d_in[10];
    const float* fc1b  = (const float*)d_in[11];
    const float* fc2w  = (const float*)d_in[12];
    const float* fc2b  = (const float*)d_in[13];
    float* out = (float*)d_out;

    if (ws_size < (size_t)230u * 1024u * 1024u) return;

    // Workspace layout:
    //   projout       0        32M    s1 -> s2
    //   weights/bmt   224M     ~2M    s0 -> end
    char* ws = (char*)d_ws;
    u16*  projout = (u16*)(ws);
    u16*  wb      = (u16*)(ws + ((size_t)224 << 20));
    u16*  qkvw_b  = wb;                // 49152
    u16*  projw_b = wb + 49152;        // 16384
    u16*  fc1w_b  = wb + 65536;        // 65536
    u16*  fc2w_b  = wb + 131072;       // 65536
    float* bmt    = (float*)(ws + ((size_t)225 << 20)); // 256 KiB

    // 0. weight conversions + bias/mask table
    cvt_kernel<<<(49152+255)/256, 256, 0, stream>>>(qkvw, qkvw_b, 49152);
    cvt_kernel<<<(16384+255)/256, 256, 0, stream>>>(projw, projw_b, 16384);
    cvt_kernel<<<(65536+255)/256, 256, 0, stream>>>(fc1w, fc1w_b, 65536);
    cvt_kernel<<<(65536+255)/256, 256, 0, stream>>>(fc2w, fc2w_b, 65536);
    bm_kernel<<<256, 256, 0, stream>>>(rpb, bmt);

    // 1. fully fused LN1 + QKV + attention + proj (512 thr; qkv in LDS)
    qkvattn_kernel<<<WTOT, 512, 0, stream>>>(
        x, n1g, n1b, qkvw_b, qkvb, bmt, projw_b, projb, projout);
    // 2. fused residual + LN2 + MLP -> out
    mlp_kernel<<<Mrows/128, 512, 0, stream>>>(
        x, projout, n2g, n2b, fc1w_b, fc1b, fc2w_b, fc2b, out);
}